// Round 1
// baseline (493.240 us; speedup 1.0000x reference)
//
#include <hip/hip_runtime.h>
#include <hip/hip_bf16.h>
#include <math.h>

// Problem constants
#define BB 8
#define TT 16
#define PP 14
#define LL 196      // P*P
#define HH 16
#define DD 64
#define DM 1024     // H*D
#define NS 16
#define T2 256      // T*T
#define LP1 197

__device__ __forceinline__ float dot4(float4 a, float4 b) {
    return a.x*b.x + a.y*b.y + a.z*b.z + a.w*b.w;
}

// ---------------------------------------------------------------------------
// Kernel 1: temporal Grams (q & k heads) + per-row softmax + 3x3 conv over the
// 32 channels -> affRaw[b*196+l][256]. One block per (b, patch l). 256 thr.
// ---------------------------------------------------------------------------
__global__ __launch_bounds__(256) void k1_temporal(
        const float* __restrict__ qin, const float* __restrict__ kin,
        const float* __restrict__ tw,  const float* __restrict__ tbv,
        float* __restrict__ affRaw) {
    __shared__ __align__(16) float lds_A[4 * 1088];    // per-wave 16x68 tile
    __shared__ __align__(16) float lds_ch[32 * 288];   // 32 ch x 16 x 18 (padded)
    __shared__ float lds_w[288];

    const int bid = blockIdx.x;
    const int b = bid / LL, l = bid % LL;
    const int tid = threadIdx.x;
    const int wave = tid >> 6, lane = tid & 63;

    for (int i = tid; i < 288; i += 256) lds_w[i] = tw[i];

    const int q2 = lane >> 3, k2 = lane & 7;
    const int qa = q2 * 2, qb = qa + 1, ka = k2 * 2, kb = ka + 1;
    float* Ap = lds_A + wave * 1088;

    const int r0 = lane >> 4, c4 = lane & 15;

    for (int cw = 0; cw < 8; ++cw) {
        const int c = cw * 4 + wave;          // channel 0..31
        const float* sp = (c < 16) ? qin : kin;
        const int h = c & 15;
        // load 16x64 tile (frames x dims) for this (b,l,h,src)
        #pragma unroll
        for (int it = 0; it < 4; ++it) {
            const int r = it * 4 + r0;
            const float4 v = *reinterpret_cast<const float4*>(
                sp + (size_t)((b * TT + r) * LP1 + 1 + l) * DM + h * DD + c4 * 4);
            *reinterpret_cast<float4*>(Ap + r * 68 + c4 * 4) = v;
        }
        // per-wave LDS ordering guarantees tile is visible (lockstep wave,
        // in-order DS ops, compiler may-alias); no cross-wave sharing of Ap.
        float a00 = 0.f, a01 = 0.f, a10 = 0.f, a11 = 0.f;
        #pragma unroll
        for (int cc = 0; cc < 16; ++cc) {
            const float4 x0 = *reinterpret_cast<const float4*>(Ap + qa * 68 + cc * 4);
            const float4 x1 = *reinterpret_cast<const float4*>(Ap + qb * 68 + cc * 4);
            const float4 y0 = *reinterpret_cast<const float4*>(Ap + ka * 68 + cc * 4);
            const float4 y1 = *reinterpret_cast<const float4*>(Ap + kb * 68 + cc * 4);
            a00 += dot4(x0, y0); a01 += dot4(x0, y1);
            a10 += dot4(x1, y0); a11 += dot4(x1, y1);
        }
        a00 *= 0.125f; a01 *= 0.125f; a10 *= 0.125f; a11 *= 0.125f;
        // softmax over k (the 16 columns) for rows qa and qb.
        // Row qa lives in the 8 lanes sharing q2 (k2=0..7), 2 values each.
        float m0 = fmaxf(a00, a01), m1 = fmaxf(a10, a11);
        #pragma unroll
        for (int msk = 1; msk < 8; msk <<= 1) {
            m0 = fmaxf(m0, __shfl_xor(m0, msk, 64));
            m1 = fmaxf(m1, __shfl_xor(m1, msk, 64));
        }
        float e00 = __expf(a00 - m0), e01 = __expf(a01 - m0);
        float e10 = __expf(a10 - m1), e11 = __expf(a11 - m1);
        float s0 = e00 + e01, s1 = e10 + e11;
        #pragma unroll
        for (int msk = 1; msk < 8; msk <<= 1) {
            s0 += __shfl_xor(s0, msk, 64);
            s1 += __shfl_xor(s1, msk, 64);
        }
        const float i0 = 1.f / s0, i1 = 1.f / s1;
        float* chp = lds_ch + c * 288;
        *reinterpret_cast<float2*>(chp + qa * 18 + ka) = make_float2(e00 * i0, e01 * i0);
        *reinterpret_cast<float2*>(chp + qb * 18 + ka) = make_float2(e10 * i1, e11 * i1);
    }
    __syncthreads();
    // 3x3 SAME conv over 32 channels; one output pixel per thread.
    const int oq = tid >> 4, ok = tid & 15;
    float s = tbv[0];
    for (int c = 0; c < 32; ++c) {
        const float* chp = lds_ch + c * 288;
        const float* wp = lds_w + c * 9;
        #pragma unroll
        for (int ky = 0; ky < 3; ++ky) {
            const int iq = oq + ky - 1;
            if (iq < 0 || iq > 15) continue;
            #pragma unroll
            for (int kx = 0; kx < 3; ++kx) {
                const int ik = ok + kx - 1;
                if (ik < 0 || ik > 15) continue;
                s += chp[iq * 18 + ik] * wp[ky * 3 + kx];
            }
        }
    }
    affRaw[(size_t)bid * T2 + tid] = s;
}

// ---------------------------------------------------------------------------
// Kernel 2: LayerNorm + MLP (gelu exact) + residual. 4 rows per block.
// ---------------------------------------------------------------------------
__global__ __launch_bounds__(256) void k2_mlp(
        const float* __restrict__ affRaw,
        const float* __restrict__ lng, const float* __restrict__ lnb,
        const float* __restrict__ w1, const float* __restrict__ b1,
        const float* __restrict__ w2, const float* __restrict__ b2,
        float* __restrict__ affRes) {
    __shared__ __align__(16) float lx[4 * 256];
    __shared__ __align__(16) float lln[4 * 256];
    __shared__ __align__(16) float lg[4 * 256];
    const int tid = threadIdx.x;
    const int wave = tid >> 6, lane = tid & 63;
    const int i0 = blockIdx.x * 4;
    {   // per-wave LN of row i0+wave
        const float* xr = affRaw + (size_t)(i0 + wave) * 256;
        float4 x = reinterpret_cast<const float4*>(xr)[lane];
        float sm = x.x + x.y + x.z + x.w;
        float ss = x.x * x.x + x.y * x.y + x.z * x.z + x.w * x.w;
        #pragma unroll
        for (int m = 1; m < 64; m <<= 1) {
            sm += __shfl_xor(sm, m, 64);
            ss += __shfl_xor(ss, m, 64);
        }
        const float mean = sm * (1.f / 256.f);
        const float var = ss * (1.f / 256.f) - mean * mean;
        const float inv = rsqrtf(var + 1e-5f);
        const float4 g4 = reinterpret_cast<const float4*>(lng)[lane];
        const float4 bb = reinterpret_cast<const float4*>(lnb)[lane];
        float4 ln;
        ln.x = (x.x - mean) * inv * g4.x + bb.x;
        ln.y = (x.y - mean) * inv * g4.y + bb.y;
        ln.z = (x.z - mean) * inv * g4.z + bb.z;
        ln.w = (x.w - mean) * inv * g4.w + bb.w;
        reinterpret_cast<float4*>(lx + wave * 256)[lane] = x;
        reinterpret_cast<float4*>(lln + wave * 256)[lane] = ln;
    }
    __syncthreads();
    const int j = tid;
    float a0 = 0.f, a1 = 0.f, a2 = 0.f, a3 = 0.f;
    {
        const float4* wr = reinterpret_cast<const float4*>(w1 + (size_t)j * 256);
        const float4* l0 = reinterpret_cast<const float4*>(lln);
        const float4* l1 = reinterpret_cast<const float4*>(lln + 256);
        const float4* l2 = reinterpret_cast<const float4*>(lln + 512);
        const float4* l3 = reinterpret_cast<const float4*>(lln + 768);
        #pragma unroll 8
        for (int m4 = 0; m4 < 64; ++m4) {
            const float4 w = wr[m4];
            a0 += dot4(w, l0[m4]); a1 += dot4(w, l1[m4]);
            a2 += dot4(w, l2[m4]); a3 += dot4(w, l3[m4]);
        }
    }
    const float bj = b1[j];
    const float kInvSqrt2 = 0.70710678118654752f;
    float h0 = a0 + bj, h1 = a1 + bj, h2 = a2 + bj, h3 = a3 + bj;
    lg[0 * 256 + j] = 0.5f * h0 * (1.f + erff(h0 * kInvSqrt2));
    lg[1 * 256 + j] = 0.5f * h1 * (1.f + erff(h1 * kInvSqrt2));
    lg[2 * 256 + j] = 0.5f * h2 * (1.f + erff(h2 * kInvSqrt2));
    lg[3 * 256 + j] = 0.5f * h3 * (1.f + erff(h3 * kInvSqrt2));
    __syncthreads();
    a0 = a1 = a2 = a3 = 0.f;
    {
        const float4* wr = reinterpret_cast<const float4*>(w2 + (size_t)j * 256);
        const float4* l0 = reinterpret_cast<const float4*>(lg);
        const float4* l1 = reinterpret_cast<const float4*>(lg + 256);
        const float4* l2 = reinterpret_cast<const float4*>(lg + 512);
        const float4* l3 = reinterpret_cast<const float4*>(lg + 768);
        #pragma unroll 8
        for (int m4 = 0; m4 < 64; ++m4) {
            const float4 w = wr[m4];
            a0 += dot4(w, l0[m4]); a1 += dot4(w, l1[m4]);
            a2 += dot4(w, l2[m4]); a3 += dot4(w, l3[m4]);
        }
    }
    const float b2j = b2[j];
    affRes[(size_t)(i0 + 0) * 256 + j] = lx[0 * 256 + j] + a0 + b2j;
    affRes[(size_t)(i0 + 1) * 256 + j] = lx[1 * 256 + j] + a1 + b2j;
    affRes[(size_t)(i0 + 2) * 256 + j] = lx[2 * 256 + j] + a2 + b2j;
    affRes[(size_t)(i0 + 3) * 256 + j] = lx[3 * 256 + j] + a3 + b2j;
}

// ---------------------------------------------------------------------------
// Kernel 3a: patch-grid 3x3 conv over 256 channels, split 64-ch per block.
// ---------------------------------------------------------------------------
__global__ __launch_bounds__(256) void k3a_pconv(
        const float* __restrict__ affRes, const float* __restrict__ pw,
        float* __restrict__ part) {
    __shared__ __align__(16) float lpw[576];
    const int b = blockIdx.x >> 2, cc = blockIdx.x & 3;
    const int tid = threadIdx.x;
    for (int idx = tid; idx < 576; idx += 256) {
        const int kk = idx / 64, c = idx & 63;
        lpw[kk * 64 + c] = pw[(size_t)(cc * 64 + c) * 9 + kk];
    }
    __syncthreads();
    if (tid < 196) {
        const int p1 = tid / 14, p2 = tid % 14;
        float s = 0.f;
        #pragma unroll
        for (int ky = 0; ky < 3; ++ky) {
            const int ip1 = p1 + ky - 1;
            if (ip1 < 0 || ip1 > 13) continue;
            #pragma unroll
            for (int kx = 0; kx < 3; ++kx) {
                const int ip2 = p2 + kx - 1;
                if (ip2 < 0 || ip2 > 13) continue;
                const float4* ar = reinterpret_cast<const float4*>(
                    affRes + (size_t)(b * LL + ip1 * 14 + ip2) * 256 + cc * 64);
                const float4* wr = reinterpret_cast<const float4*>(lpw + (ky * 3 + kx) * 64);
                #pragma unroll
                for (int c4 = 0; c4 < 16; ++c4) s += dot4(ar[c4], wr[c4]);
            }
        }
        part[(cc * 8 + b) * 196 + tid] = s;
    }
}

__global__ void k3b_yt(const float* __restrict__ part,
                       const float* __restrict__ pcb, float* __restrict__ out) {
    const int b = blockIdx.x, tid = threadIdx.x;
    if (tid < 196) {
        float s = pcb[0];
        #pragma unroll
        for (int cc = 0; cc < 4; ++cc) s += part[(cc * 8 + b) * 196 + tid];
        out[b * 196 + tid] = s;
    }
}

// ---------------------------------------------------------------------------
// Kernel 4a: spatial logits  SL[b,t,q,l] = (1/32) * dot(syno[q], kf[b,t,l])
// ---------------------------------------------------------------------------
__global__ __launch_bounds__(256) void k4a_logits(
        const float* __restrict__ kin, const float* __restrict__ syno,
        float* __restrict__ SL) {
    const int lt = blockIdx.x, t = blockIdx.y, b = blockIdx.z;
    const int tid = threadIdx.x;
    const int qq = tid >> 4, ls = tid & 15;
    const int l = lt * 16 + ls;
    if (l >= LL) return;
    const float4* sp = reinterpret_cast<const float4*>(syno + (size_t)qq * DM);
    const float4* kp = reinterpret_cast<const float4*>(
        kin + (size_t)((b * TT + t) * LP1 + 1 + l) * DM);
    float acc = 0.f;
    #pragma unroll 8
    for (int w4 = 0; w4 < 256; ++w4) acc += dot4(sp[w4], kp[w4]);
    SL[(size_t)((b * TT + t) * NS + qq) * LL + l] = acc * 0.03125f;
}

// Kernel 4b: softmax over l per (b,t,q) + sum over q -> WSUM[b,t,l]
__global__ __launch_bounds__(256) void k4b_softmax(
        const float* __restrict__ SL, float* __restrict__ WSUM) {
    __shared__ float lp[16 * 200];
    const int t = blockIdx.x, b = blockIdx.y;
    const int tid = threadIdx.x;
    const int qq = tid >> 4, j = tid & 15;
    const float* row = SL + (size_t)((b * TT + t) * NS + qq) * LL;
    float v[13];
    float m = -1e30f;
    #pragma unroll
    for (int i = 0; i < 13; ++i) {
        const int l = j + i * 16;
        v[i] = (l < LL) ? row[l] : -1e30f;
        m = fmaxf(m, v[i]);
    }
    #pragma unroll
    for (int msk = 1; msk < 16; msk <<= 1) m = fmaxf(m, __shfl_xor(m, msk, 64));
    float s = 0.f;
    #pragma unroll
    for (int i = 0; i < 13; ++i) {
        const int l = j + i * 16;
        v[i] = (l < LL) ? __expf(v[i] - m) : 0.f;
        s += v[i];
    }
    #pragma unroll
    for (int msk = 1; msk < 16; msk <<= 1) s += __shfl_xor(s, msk, 64);
    const float inv = 1.f / s;
    #pragma unroll
    for (int i = 0; i < 13; ++i) {
        const int l = j + i * 16;
        if (l < LL) lp[qq * 200 + l] = v[i] * inv;
    }
    __syncthreads();
    if (tid < LL) {
        float w = 0.f;
        #pragma unroll
        for (int qi = 0; qi < 16; ++qi) w += lp[qi * 200 + tid];
        WSUM[(size_t)(b * TT + t) * LL + tid] = w;
    }
}

// Kernel 4c: PS[b,t,:] = sum_l WSUM[b,t,l] * v[b,t,l,:]
__global__ __launch_bounds__(256) void k4c_vsum(
        const float* __restrict__ vin, const float* __restrict__ WSUM,
        float* __restrict__ PS) {
    __shared__ float lw[196];
    const int t = blockIdx.x, b = blockIdx.y;
    const int tid = threadIdx.x;
    if (tid < LL) lw[tid] = WSUM[(size_t)(b * TT + t) * LL + tid];
    __syncthreads();
    float4 acc = make_float4(0.f, 0.f, 0.f, 0.f);
    const float* vb = vin + (size_t)((b * TT + t) * LP1 + 1) * DM + tid * 4;
    #pragma unroll 4
    for (int l = 0; l < LL; ++l) {
        const float4 v = *reinterpret_cast<const float4*>(vb + (size_t)l * DM);
        const float w = lw[l];
        acc.x += w * v.x; acc.y += w * v.y; acc.z += w * v.z; acc.w += w * v.w;
    }
    *reinterpret_cast<float4*>(PS + (size_t)(b * TT + t) * DM + tid * 4) = acc;
}

// Kernel 4d: y_s[b,w] = (1/256) * sum_t PS[b,t,w]
__global__ void k4d_ys(const float* __restrict__ PS, float* __restrict__ out) {
    const int i = blockIdx.x * 256 + threadIdx.x;   // 0..8191
    const int b = i >> 10, w = i & 1023;
    float s = 0.f;
    #pragma unroll
    for (int t = 0; t < TT; ++t) s += PS[(size_t)(b * TT + t) * DM + w];
    out[1568 + i] = s * (1.f / 256.f);
}

// ---------------------------------------------------------------------------
extern "C" void kernel_launch(void* const* d_in, const int* in_sizes, int n_in,
                              void* d_out, int out_size, void* d_ws, size_t ws_size,
                              hipStream_t stream) {
    const float* q    = (const float*)d_in[0];
    const float* k    = (const float*)d_in[1];
    const float* v    = (const float*)d_in[2];
    const float* syno = (const float*)d_in[3];
    const float* tw   = (const float*)d_in[4];
    const float* tbv  = (const float*)d_in[5];
    const float* lng  = (const float*)d_in[6];
    const float* lnb  = (const float*)d_in[7];
    const float* w1   = (const float*)d_in[8];
    const float* b1   = (const float*)d_in[9];
    const float* w2   = (const float*)d_in[10];
    const float* b2   = (const float*)d_in[11];
    const float* pw   = (const float*)d_in[12];
    const float* pcb  = (const float*)d_in[13];
    float* out = (float*)d_out;

    float* ws = (float*)d_ws;
    float* affRaw = ws;                 // 1568*256 = 401408
    float* affRes = ws + 401408;        // 401408
    float* SL     = ws + 802816;        // 8*16*16*196 = 401408
    float* WSUM   = ws + 1204224;       // 8*16*196 = 25088
    float* PS     = ws + 1229312;       // 8*16*1024 = 131072
    float* part   = ws + 1360384;       // 4*8*196 = 6272

    // temporal path
    hipLaunchKernelGGL(k1_temporal, dim3(BB * LL), dim3(256), 0, stream,
                       q, k, tw, tbv, affRaw);
    hipLaunchKernelGGL(k2_mlp, dim3(392), dim3(256), 0, stream,
                       affRaw, lng, lnb, w1, b1, w2, b2, affRes);
    hipLaunchKernelGGL(k3a_pconv, dim3(32), dim3(256), 0, stream,
                       affRes, pw, part);
    hipLaunchKernelGGL(k3b_yt, dim3(8), dim3(256), 0, stream, part, pcb, out);
    // spatial path
    hipLaunchKernelGGL(k4a_logits, dim3(13, 16, 8), dim3(256), 0, stream,
                       k, syno, SL);
    hipLaunchKernelGGL(k4b_softmax, dim3(16, 8), dim3(256), 0, stream, SL, WSUM);
    hipLaunchKernelGGL(k4c_vsum, dim3(16, 8), dim3(256), 0, stream, v, WSUM, PS);
    hipLaunchKernelGGL(k4d_ys, dim3(32), dim3(256), 0, stream, PS, out);
}

// Round 4
// 317.938 us; speedup vs baseline: 1.5514x; 1.5514x over previous
//
#include <hip/hip_runtime.h>
#include <hip/hip_bf16.h>
#include <math.h>

// Problem constants
#define BB 8
#define TT 16
#define PP 14
#define LL 196      // P*P
#define HH 16
#define DD 64
#define DM 1024     // H*D
#define NS 16
#define T2 256      // T*T
#define LP1 197

__device__ __forceinline__ float dot4(float4 a, float4 b) {
    return a.x*b.x + a.y*b.y + a.z*b.z + a.w*b.w;
}

// ---------------------------------------------------------------------------
// Kernel 1: temporal Grams (q & k heads) + per-row softmax + 3x3 conv over the
// 32 channels -> affRaw[b*196+l][256]. One block per (b, patch l). 256 thr.
// (Exact R1 implementation — fp32 VALU; k1 is HBM-bound so MFMA is not needed.)
// ---------------------------------------------------------------------------
__global__ __launch_bounds__(256) void k1_temporal(
        const float* __restrict__ qin, const float* __restrict__ kin,
        const float* __restrict__ tw,  const float* __restrict__ tbv,
        float* __restrict__ affRaw) {
    __shared__ __align__(16) float lds_A[4 * 1088];    // per-wave 16x68 tile
    __shared__ __align__(16) float lds_ch[32 * 288];   // 32 ch x 16 x 18 (padded)
    __shared__ float lds_w[288];

    const int bid = blockIdx.x;
    const int b = bid / LL, l = bid % LL;
    const int tid = threadIdx.x;
    const int wave = tid >> 6, lane = tid & 63;

    for (int i = tid; i < 288; i += 256) lds_w[i] = tw[i];

    const int q2 = lane >> 3, k2 = lane & 7;
    const int qa = q2 * 2, qb = qa + 1, ka = k2 * 2, kb = ka + 1;
    float* Ap = lds_A + wave * 1088;

    const int r0 = lane >> 4, c4 = lane & 15;

    for (int cw = 0; cw < 8; ++cw) {
        const int c = cw * 4 + wave;          // channel 0..31
        const float* sp = (c < 16) ? qin : kin;
        const int h = c & 15;
        // load 16x64 tile (frames x dims) for this (b,l,h,src)
        #pragma unroll
        for (int it = 0; it < 4; ++it) {
            const int r = it * 4 + r0;
            const float4 v = *reinterpret_cast<const float4*>(
                sp + (size_t)((b * TT + r) * LP1 + 1 + l) * DM + h * DD + c4 * 4);
            *reinterpret_cast<float4*>(Ap + r * 68 + c4 * 4) = v;
        }
        // per-wave LDS ordering guarantees tile is visible (lockstep wave,
        // in-order DS ops, compiler may-alias); no cross-wave sharing of Ap.
        float a00 = 0.f, a01 = 0.f, a10 = 0.f, a11 = 0.f;
        #pragma unroll
        for (int cc = 0; cc < 16; ++cc) {
            const float4 x0 = *reinterpret_cast<const float4*>(Ap + qa * 68 + cc * 4);
            const float4 x1 = *reinterpret_cast<const float4*>(Ap + qb * 68 + cc * 4);
            const float4 y0 = *reinterpret_cast<const float4*>(Ap + ka * 68 + cc * 4);
            const float4 y1 = *reinterpret_cast<const float4*>(Ap + kb * 68 + cc * 4);
            a00 += dot4(x0, y0); a01 += dot4(x0, y1);
            a10 += dot4(x1, y0); a11 += dot4(x1, y1);
        }
        a00 *= 0.125f; a01 *= 0.125f; a10 *= 0.125f; a11 *= 0.125f;
        // softmax over k (the 16 columns) for rows qa and qb.
        // Row qa lives in the 8 lanes sharing q2 (k2=0..7), 2 values each.
        float m0 = fmaxf(a00, a01), m1 = fmaxf(a10, a11);
        #pragma unroll
        for (int msk = 1; msk < 8; msk <<= 1) {
            m0 = fmaxf(m0, __shfl_xor(m0, msk, 64));
            m1 = fmaxf(m1, __shfl_xor(m1, msk, 64));
        }
        float e00 = __expf(a00 - m0), e01 = __expf(a01 - m0);
        float e10 = __expf(a10 - m1), e11 = __expf(a11 - m1);
        float s0 = e00 + e01, s1 = e10 + e11;
        #pragma unroll
        for (int msk = 1; msk < 8; msk <<= 1) {
            s0 += __shfl_xor(s0, msk, 64);
            s1 += __shfl_xor(s1, msk, 64);
        }
        const float i0 = 1.f / s0, i1 = 1.f / s1;
        float* chp = lds_ch + c * 288;
        *reinterpret_cast<float2*>(chp + qa * 18 + ka) = make_float2(e00 * i0, e01 * i0);
        *reinterpret_cast<float2*>(chp + qb * 18 + ka) = make_float2(e10 * i1, e11 * i1);
    }
    __syncthreads();
    // 3x3 SAME conv over 32 channels; one output pixel per thread.
    const int oq = tid >> 4, ok = tid & 15;
    float s = tbv[0];
    for (int c = 0; c < 32; ++c) {
        const float* chp = lds_ch + c * 288;
        const float* wp = lds_w + c * 9;
        #pragma unroll
        for (int ky = 0; ky < 3; ++ky) {
            const int iq = oq + ky - 1;
            if (iq < 0 || iq > 15) continue;
            #pragma unroll
            for (int kx = 0; kx < 3; ++kx) {
                const int ik = ok + kx - 1;
                if (ik < 0 || ik > 15) continue;
                s += chp[iq * 18 + ik] * wp[ky * 3 + kx];
            }
        }
    }
    affRaw[(size_t)bid * T2 + tid] = s;
}

// ---------------------------------------------------------------------------
// Kernel 2: LayerNorm + MLP (gelu exact) + residual. 4 rows per block.
// ---------------------------------------------------------------------------
__global__ __launch_bounds__(256) void k2_mlp(
        const float* __restrict__ affRaw,
        const float* __restrict__ lng, const float* __restrict__ lnb,
        const float* __restrict__ w1, const float* __restrict__ b1,
        const float* __restrict__ w2, const float* __restrict__ b2,
        float* __restrict__ affRes) {
    __shared__ __align__(16) float lx[4 * 256];
    __shared__ __align__(16) float lln[4 * 256];
    __shared__ __align__(16) float lg[4 * 256];
    const int tid = threadIdx.x;
    const int wave = tid >> 6, lane = tid & 63;
    const int i0 = blockIdx.x * 4;
    {
        const float* xr = affRaw + (size_t)(i0 + wave) * 256;
        float4 x = reinterpret_cast<const float4*>(xr)[lane];
        float sm = x.x + x.y + x.z + x.w;
        float ss = x.x * x.x + x.y * x.y + x.z * x.z + x.w * x.w;
        #pragma unroll
        for (int m = 1; m < 64; m <<= 1) {
            sm += __shfl_xor(sm, m, 64);
            ss += __shfl_xor(ss, m, 64);
        }
        const float mean = sm * (1.f / 256.f);
        const float var = ss * (1.f / 256.f) - mean * mean;
        const float inv = rsqrtf(var + 1e-5f);
        const float4 g4 = reinterpret_cast<const float4*>(lng)[lane];
        const float4 bb = reinterpret_cast<const float4*>(lnb)[lane];
        float4 ln;
        ln.x = (x.x - mean) * inv * g4.x + bb.x;
        ln.y = (x.y - mean) * inv * g4.y + bb.y;
        ln.z = (x.z - mean) * inv * g4.z + bb.z;
        ln.w = (x.w - mean) * inv * g4.w + bb.w;
        reinterpret_cast<float4*>(lx + wave * 256)[lane] = x;
        reinterpret_cast<float4*>(lln + wave * 256)[lane] = ln;
    }
    __syncthreads();
    const int j = tid;
    float a0 = 0.f, a1 = 0.f, a2 = 0.f, a3 = 0.f;
    {
        const float4* wr = reinterpret_cast<const float4*>(w1 + (size_t)j * 256);
        const float4* l0 = reinterpret_cast<const float4*>(lln);
        const float4* l1 = reinterpret_cast<const float4*>(lln + 256);
        const float4* l2 = reinterpret_cast<const float4*>(lln + 512);
        const float4* l3 = reinterpret_cast<const float4*>(lln + 768);
        #pragma unroll 8
        for (int m4 = 0; m4 < 64; ++m4) {
            const float4 w = wr[m4];
            a0 += dot4(w, l0[m4]); a1 += dot4(w, l1[m4]);
            a2 += dot4(w, l2[m4]); a3 += dot4(w, l3[m4]);
        }
    }
    const float bj = b1[j];
    const float kInvSqrt2 = 0.70710678118654752f;
    float h0 = a0 + bj, h1 = a1 + bj, h2 = a2 + bj, h3 = a3 + bj;
    lg[0 * 256 + j] = 0.5f * h0 * (1.f + erff(h0 * kInvSqrt2));
    lg[1 * 256 + j] = 0.5f * h1 * (1.f + erff(h1 * kInvSqrt2));
    lg[2 * 256 + j] = 0.5f * h2 * (1.f + erff(h2 * kInvSqrt2));
    lg[3 * 256 + j] = 0.5f * h3 * (1.f + erff(h3 * kInvSqrt2));
    __syncthreads();
    a0 = a1 = a2 = a3 = 0.f;
    {
        const float4* wr = reinterpret_cast<const float4*>(w2 + (size_t)j * 256);
        const float4* l0 = reinterpret_cast<const float4*>(lg);
        const float4* l1 = reinterpret_cast<const float4*>(lg + 256);
        const float4* l2 = reinterpret_cast<const float4*>(lg + 512);
        const float4* l3 = reinterpret_cast<const float4*>(lg + 768);
        #pragma unroll 8
        for (int m4 = 0; m4 < 64; ++m4) {
            const float4 w = wr[m4];
            a0 += dot4(w, l0[m4]); a1 += dot4(w, l1[m4]);
            a2 += dot4(w, l2[m4]); a3 += dot4(w, l3[m4]);
        }
    }
    const float b2j = b2[j];
    affRes[(size_t)(i0 + 0) * 256 + j] = lx[0 * 256 + j] + a0 + b2j;
    affRes[(size_t)(i0 + 1) * 256 + j] = lx[1 * 256 + j] + a1 + b2j;
    affRes[(size_t)(i0 + 2) * 256 + j] = lx[2 * 256 + j] + a2 + b2j;
    affRes[(size_t)(i0 + 3) * 256 + j] = lx[3 * 256 + j] + a3 + b2j;
}

// ---------------------------------------------------------------------------
// Kernel 3a: patch-grid 3x3 conv over 256 channels, split 64-ch per block.
// ---------------------------------------------------------------------------
__global__ __launch_bounds__(256) void k3a_pconv(
        const float* __restrict__ affRes, const float* __restrict__ pw,
        float* __restrict__ part) {
    __shared__ __align__(16) float lpw[576];
    const int b = blockIdx.x >> 2, cc = blockIdx.x & 3;
    const int tid = threadIdx.x;
    for (int idx = tid; idx < 576; idx += 256) {
        const int kk = idx / 64, c = idx & 63;
        lpw[kk * 64 + c] = pw[(size_t)(cc * 64 + c) * 9 + kk];
    }
    __syncthreads();
    if (tid < 196) {
        const int p1 = tid / 14, p2 = tid % 14;
        float s = 0.f;
        #pragma unroll
        for (int ky = 0; ky < 3; ++ky) {
            const int ip1 = p1 + ky - 1;
            if (ip1 < 0 || ip1 > 13) continue;
            #pragma unroll
            for (int kx = 0; kx < 3; ++kx) {
                const int ip2 = p2 + kx - 1;
                if (ip2 < 0 || ip2 > 13) continue;
                const float4* ar = reinterpret_cast<const float4*>(
                    affRes + (size_t)(b * LL + ip1 * 14 + ip2) * 256 + cc * 64);
                const float4* wr = reinterpret_cast<const float4*>(lpw + (ky * 3 + kx) * 64);
                #pragma unroll
                for (int c4 = 0; c4 < 16; ++c4) s += dot4(ar[c4], wr[c4]);
            }
        }
        part[(cc * 8 + b) * 196 + tid] = s;
    }
}

__global__ void k3b_yt(const float* __restrict__ part,
                       const float* __restrict__ pcb, float* __restrict__ out) {
    const int b = blockIdx.x, tid = threadIdx.x;
    if (tid < 196) {
        float s = pcb[0];
        #pragma unroll
        for (int cc = 0; cc < 4; ++cc) s += part[(cc * 8 + b) * 196 + tid];
        out[b * 196 + tid] = s;
    }
}

// ---------------------------------------------------------------------------
// Kernel 4a: SL[btq][l] = (1/32)*dot(syno[q], k-row). One thread per
// (row, D-quarter); 16 acc per thread; block = 64 rows x 4 D-quarters.
// ---------------------------------------------------------------------------
__global__ __launch_bounds__(256) void k4a_new(
        const float* __restrict__ kin, const float* __restrict__ syno,
        float* __restrict__ SL) {
    __shared__ float red[4][64][17];
    const int tid = threadIdx.x, wid = tid >> 6, lane = tid & 63;
    const int dq = __builtin_amdgcn_readfirstlane(wid);
    const int row = blockIdx.x * 64 + lane;          // 0..25087 (392*64 exact)
    const int bt = row / 196, l = row % 196;
    const float* kp = kin + ((size_t)(bt * LP1 + 1 + l)) * DM + dq * 256;
    const float* sp = syno + dq * 256;
    float acc[16];
    #pragma unroll
    for (int q = 0; q < 16; ++q) acc[q] = 0.f;
    #pragma unroll 4
    for (int c = 0; c < 64; ++c) {
        const float4 kv = reinterpret_cast<const float4*>(kp)[c];
        #pragma unroll
        for (int q = 0; q < 16; ++q) {
            const float4 sv = reinterpret_cast<const float4*>(sp + q * 1024)[c];
            acc[q] += dot4(kv, sv);
        }
    }
    #pragma unroll
    for (int q = 0; q < 16; ++q) red[wid][lane][q] = acc[q];
    __syncthreads();
    const int lrow = tid >> 2, q0 = (tid & 3) * 4;
    const int grow = blockIdx.x * 64 + lrow;
    const int bt2 = grow / 196, l2 = grow % 196;
    #pragma unroll
    for (int jj = 0; jj < 4; ++jj) {
        const float s = red[0][lrow][q0 + jj] + red[1][lrow][q0 + jj] +
                        red[2][lrow][q0 + jj] + red[3][lrow][q0 + jj];
        SL[((size_t)bt2 * NS + q0 + jj) * LL + l2] = s * 0.03125f;
    }
}

// Kernel 4b: softmax over l per (b,t,q) + sum over q -> WSUM[b,t,l]
__global__ __launch_bounds__(256) void k4b_softmax(
        const float* __restrict__ SL, float* __restrict__ WSUM) {
    __shared__ float lp[16 * 200];
    const int t = blockIdx.x, b = blockIdx.y;
    const int tid = threadIdx.x;
    const int qq = tid >> 4, j = tid & 15;
    const float* row = SL + (size_t)((b * TT + t) * NS + qq) * LL;
    float v[13];
    float m = -1e30f;
    #pragma unroll
    for (int i = 0; i < 13; ++i) {
        const int l = j + i * 16;
        v[i] = (l < LL) ? row[l] : -1e30f;
        m = fmaxf(m, v[i]);
    }
    #pragma unroll
    for (int msk = 1; msk < 16; msk <<= 1) m = fmaxf(m, __shfl_xor(m, msk, 64));
    float s = 0.f;
    #pragma unroll
    for (int i = 0; i < 13; ++i) {
        const int l = j + i * 16;
        v[i] = (l < LL) ? __expf(v[i] - m) : 0.f;
        s += v[i];
    }
    #pragma unroll
    for (int msk = 1; msk < 16; msk <<= 1) s += __shfl_xor(s, msk, 64);
    const float inv = 1.f / s;
    #pragma unroll
    for (int i = 0; i < 13; ++i) {
        const int l = j + i * 16;
        if (l < LL) lp[qq * 200 + l] = v[i] * inv;
    }
    __syncthreads();
    if (tid < LL) {
        float w = 0.f;
        #pragma unroll
        for (int qi = 0; qi < 16; ++qi) w += lp[qi * 200 + tid];
        WSUM[(size_t)(b * TT + t) * LL + tid] = w;
    }
}

// Kernel 4c: PS[bt][z][:] = sum over 98 rows of WSUM * v  (z-split over l)
__global__ __launch_bounds__(256) void k4c_vsum(
        const float* __restrict__ vin, const float* __restrict__ WSUM,
        float* __restrict__ PS) {
    __shared__ float lw[98];
    const int t = blockIdx.x, b = blockIdx.y, z = blockIdx.z;
    const int tid = threadIdx.x;
    const int bt = b * TT + t;
    if (tid < 98) lw[tid] = WSUM[(size_t)bt * LL + z * 98 + tid];
    __syncthreads();
    float4 acc = make_float4(0.f, 0.f, 0.f, 0.f);
    const float* vb = vin + ((size_t)bt * LP1 + 1 + z * 98) * DM + tid * 4;
    #pragma unroll 4
    for (int l = 0; l < 98; ++l) {
        const float4 v = *reinterpret_cast<const float4*>(vb + (size_t)l * DM);
        const float w = lw[l];
        acc.x += w * v.x; acc.y += w * v.y; acc.z += w * v.z; acc.w += w * v.w;
    }
    *reinterpret_cast<float4*>(PS + ((size_t)bt * 2 + z) * DM + tid * 4) = acc;
}

// Kernel 4d: y_s[b,w] = (1/256) * sum over 32 (t,z) partials
__global__ void k4d_ys(const float* __restrict__ PS, float* __restrict__ out) {
    const int i = blockIdx.x * 256 + threadIdx.x;   // 0..8191
    const int b = i >> 10, w = i & 1023;
    float s = 0.f;
    #pragma unroll
    for (int tz = 0; tz < 32; ++tz) s += PS[((size_t)b * 32 + tz) * DM + w];
    out[1568 + i] = s * (1.f / 256.f);
}

// ---------------------------------------------------------------------------
extern "C" void kernel_launch(void* const* d_in, const int* in_sizes, int n_in,
                              void* d_out, int out_size, void* d_ws, size_t ws_size,
                              hipStream_t stream) {
    const float* q    = (const float*)d_in[0];
    const float* k    = (const float*)d_in[1];
    const float* v    = (const float*)d_in[2];
    const float* syno = (const float*)d_in[3];
    const float* tw   = (const float*)d_in[4];
    const float* tbv  = (const float*)d_in[5];
    const float* lng  = (const float*)d_in[6];
    const float* lnb  = (const float*)d_in[7];
    const float* w1   = (const float*)d_in[8];
    const float* b1   = (const float*)d_in[9];
    const float* w2   = (const float*)d_in[10];
    const float* b2   = (const float*)d_in[11];
    const float* pw   = (const float*)d_in[12];
    const float* pcb  = (const float*)d_in[13];
    float* out = (float*)d_out;

    float* ws = (float*)d_ws;
    float* affRaw = ws;                 // 401408 floats (dead after k2)
    float* affRes = ws + 401408;        // 401408
    float* SL     = ws + 802816;        // 401408
    float* WSUM   = ws + 1204224;       // 25088
    float* part   = ws + 1229312;       // 6272
    float* PS     = ws;                 // 262144, aliases affRaw (k4c after k2)

    // temporal path
    hipLaunchKernelGGL(k1_temporal, dim3(BB * LL), dim3(256), 0, stream,
                       q, k, tw, tbv, affRaw);
    hipLaunchKernelGGL(k2_mlp, dim3(392), dim3(256), 0, stream,
                       affRaw, lng, lnb, w1, b1, w2, b2, affRes);
    hipLaunchKernelGGL(k3a_pconv, dim3(32), dim3(256), 0, stream,
                       affRes, pw, part);
    hipLaunchKernelGGL(k3b_yt, dim3(8), dim3(256), 0, stream, part, pcb, out);
    // spatial path
    hipLaunchKernelGGL(k4a_new, dim3(392), dim3(256), 0, stream, k, syno, SL);
    hipLaunchKernelGGL(k4b_softmax, dim3(16, 8), dim3(256), 0, stream, SL, WSUM);
    hipLaunchKernelGGL(k4c_vsum, dim3(16, 8, 2), dim3(256), 0, stream, v, WSUM, PS);
    hipLaunchKernelGGL(k4d_ys, dim3(32), dim3(256), 0, stream, PS, out);
}

// Round 5
// 237.089 us; speedup vs baseline: 2.0804x; 1.3410x over previous
//
#include <hip/hip_runtime.h>
#include <hip/hip_bf16.h>
#include <math.h>

// Problem constants
#define BB 8
#define TT 16
#define PP 14
#define LL 196      // P*P
#define HH 16
#define DD 64
#define DM 1024     // H*D
#define NS 16
#define T2 256      // T*T
#define LP1 197

__device__ __forceinline__ float dot4(float4 a, float4 b) {
    return a.x*b.x + a.y*b.y + a.z*b.z + a.w*b.w;
}

// ---------------------------------------------------------------------------
// Kernel 1 (v2): temporal Grams + softmax + fused 3x3 conv.
// One block per (b, patch l), 256 threads = 4 waves.
// - 4x4 register tiling: lane (cl,q4,k4) computes S[4q4+r][4k4+j] for its
//   wave's channel (chp*16 + w*4 + cl). 8 b128 LDS reads per 64 FMA.
// - A staged in dim-quarters (16 dims): lA[16ch][16row][20], ch-stride 324
//   (both strides chosen so per-instr lanes spread 8 bank-groups, 2-way=free).
// - Softmax rows in-lane + 2 shfl_xor rounds over k4 lanes (cols = key axis).
// - Conv fused per 16-channel pass via lP[4grp][256pix][4ch] float4 buffer.
// LDS total ~38.3 KB -> 4 blocks/CU (was 55.8 KB -> 2).
// ---------------------------------------------------------------------------
__global__ __launch_bounds__(256) void k1_temporal(
        const float* __restrict__ qin, const float* __restrict__ kin,
        const float* __restrict__ tw,  const float* __restrict__ tbv,
        float* __restrict__ affRaw) {
    __shared__ __align__(16) float lA[5184];   // [16ch][16row][20], ch-stride 324
    __shared__ __align__(16) float lP[4096];   // [4g][256pix][4cl]
    __shared__ __align__(16) float lW[288];    // [chp][g][tap][cl]
    const int bid = blockIdx.x, b = bid / LL, l = bid % LL;
    const int tid = threadIdx.x, w = tid >> 6, lane = tid & 63;
    const int cl = (lane >> 4) & 3, q4 = (lane >> 2) & 3, k4 = lane & 3;

    // stage conv weights reordered to [chp][g][tap][cl]
    for (int i = tid; i < 288; i += 256) {
        const int ccl = i & 3, tap = (i >> 2) % 9, g = (i / 36) & 3, chp = i / 144;
        lW[i] = tw[(chp * 16 + g * 4 + ccl) * 9 + tap];
    }

    const int sch = tid >> 4, srow = tid & 15;   // staging: 1 thread per (ch,row)
    const int oq = tid >> 4, ok = tid & 15;      // conv: 1 thread per out pixel
    float convAcc = tbv[0];

    const float* cb = lA + (w * 4 + cl) * 324;   // this lane's channel tile
    const int xr0 = 4 * q4, yr0 = 4 * k4;

    for (int chp = 0; chp < 2; ++chp) {
        const int chg = chp * 16 + sch;
        const float* sp = (chg < 16) ? qin : kin;
        const float* rowp = sp + ((size_t)(b * TT + srow) * LP1 + 1 + l) * DM
                            + (size_t)(chg & 15) * DD;
        float* wdst = lA + sch * 324 + srow * 20;

        float acc[4][4];
        #pragma unroll
        for (int r = 0; r < 4; ++r)
            #pragma unroll
            for (int j = 0; j < 4; ++j) acc[r][j] = 0.f;

        for (int dp = 0; dp < 4; ++dp) {
            // issue global loads before the barrier (overlap)
            const float4 t0 = *reinterpret_cast<const float4*>(rowp + dp * 16);
            const float4 t1 = *reinterpret_cast<const float4*>(rowp + dp * 16 + 4);
            const float4 t2 = *reinterpret_cast<const float4*>(rowp + dp * 16 + 8);
            const float4 t3 = *reinterpret_cast<const float4*>(rowp + dp * 16 + 12);
            __syncthreads();   // previous quarter's readers done
            reinterpret_cast<float4*>(wdst)[0] = t0;
            reinterpret_cast<float4*>(wdst)[1] = t1;
            reinterpret_cast<float4*>(wdst)[2] = t2;
            reinterpret_cast<float4*>(wdst)[3] = t3;
            __syncthreads();
            #pragma unroll
            for (int cc = 0; cc < 4; ++cc) {
                float4 x[4], y[4];
                #pragma unroll
                for (int r = 0; r < 4; ++r)
                    x[r] = *reinterpret_cast<const float4*>(cb + (xr0 + r) * 20 + cc * 4);
                #pragma unroll
                for (int j = 0; j < 4; ++j)
                    y[j] = *reinterpret_cast<const float4*>(cb + (yr0 + j) * 20 + cc * 4);
                #pragma unroll
                for (int r = 0; r < 4; ++r)
                    #pragma unroll
                    for (int j = 0; j < 4; ++j)
                        acc[r][j] += dot4(x[r], y[j]);
            }
        }
        // scale + softmax over cols (key axis): in-lane 4 + shfl over k4 lanes
        float p[4][4];
        #pragma unroll
        for (int r = 0; r < 4; ++r) {
            const float s0 = acc[r][0] * 0.125f, s1 = acc[r][1] * 0.125f;
            const float s2 = acc[r][2] * 0.125f, s3 = acc[r][3] * 0.125f;
            float m = fmaxf(fmaxf(s0, s1), fmaxf(s2, s3));
            m = fmaxf(m, __shfl_xor(m, 1, 64));
            m = fmaxf(m, __shfl_xor(m, 2, 64));
            const float e0 = __expf(s0 - m), e1 = __expf(s1 - m);
            const float e2 = __expf(s2 - m), e3 = __expf(s3 - m);
            float rs = e0 + e1 + e2 + e3;
            rs += __shfl_xor(rs, 1, 64);
            rs += __shfl_xor(rs, 2, 64);
            const float inv = 1.f / rs;
            p[r][0] = e0 * inv; p[r][1] = e1 * inv;
            p[r][2] = e2 * inv; p[r][3] = e3 * inv;
        }
        // write P: group g = wave, slot = cl
        float* pb = lP + w * 1024;
        #pragma unroll
        for (int r = 0; r < 4; ++r)
            #pragma unroll
            for (int j = 0; j < 4; ++j)
                pb[((xr0 + r) * 16 + yr0 + j) * 4 + cl] = p[r][j];
        __syncthreads();
        // conv partial over this pass's 16 channels
        #pragma unroll
        for (int ky = 0; ky < 3; ++ky) {
            const int iq = oq + ky - 1;
            if (iq < 0 || iq > 15) continue;
            #pragma unroll
            for (int kx = 0; kx < 3; ++kx) {
                const int ik = ok + kx - 1;
                if (ik < 0 || ik > 15) continue;
                const int pofs = (iq * 16 + ik) * 4;
                #pragma unroll
                for (int g = 0; g < 4; ++g) {
                    const float4 pd = *reinterpret_cast<const float4*>(lP + g * 1024 + pofs);
                    const float4 wv = *reinterpret_cast<const float4*>(
                        lW + ((chp * 4 + g) * 9 + ky * 3 + kx) * 4);
                    convAcc += dot4(pd, wv);
                }
            }
        }
        __syncthreads();   // before next pass overwrites lA/lP
    }
    affRaw[(size_t)bid * T2 + tid] = convAcc;
}

// ---------------------------------------------------------------------------
// Kernel 2: LayerNorm + MLP (gelu exact) + residual. 4 rows per block.
// ---------------------------------------------------------------------------
__global__ __launch_bounds__(256) void k2_mlp(
        const float* __restrict__ affRaw,
        const float* __restrict__ lng, const float* __restrict__ lnb,
        const float* __restrict__ w1, const float* __restrict__ b1,
        const float* __restrict__ w2, const float* __restrict__ b2,
        float* __restrict__ affRes) {
    __shared__ __align__(16) float lx[4 * 256];
    __shared__ __align__(16) float lln[4 * 256];
    __shared__ __align__(16) float lg[4 * 256];
    const int tid = threadIdx.x;
    const int wave = tid >> 6, lane = tid & 63;
    const int i0 = blockIdx.x * 4;
    {
        const float* xr = affRaw + (size_t)(i0 + wave) * 256;
        float4 x = reinterpret_cast<const float4*>(xr)[lane];
        float sm = x.x + x.y + x.z + x.w;
        float ss = x.x * x.x + x.y * x.y + x.z * x.z + x.w * x.w;
        #pragma unroll
        for (int m = 1; m < 64; m <<= 1) {
            sm += __shfl_xor(sm, m, 64);
            ss += __shfl_xor(ss, m, 64);
        }
        const float mean = sm * (1.f / 256.f);
        const float var = ss * (1.f / 256.f) - mean * mean;
        const float inv = rsqrtf(var + 1e-5f);
        const float4 g4 = reinterpret_cast<const float4*>(lng)[lane];
        const float4 bb = reinterpret_cast<const float4*>(lnb)[lane];
        float4 ln;
        ln.x = (x.x - mean) * inv * g4.x + bb.x;
        ln.y = (x.y - mean) * inv * g4.y + bb.y;
        ln.z = (x.z - mean) * inv * g4.z + bb.z;
        ln.w = (x.w - mean) * inv * g4.w + bb.w;
        reinterpret_cast<float4*>(lx + wave * 256)[lane] = x;
        reinterpret_cast<float4*>(lln + wave * 256)[lane] = ln;
    }
    __syncthreads();
    const int j = tid;
    float a0 = 0.f, a1 = 0.f, a2 = 0.f, a3 = 0.f;
    {
        const float4* wr = reinterpret_cast<const float4*>(w1 + (size_t)j * 256);
        const float4* l0 = reinterpret_cast<const float4*>(lln);
        const float4* l1 = reinterpret_cast<const float4*>(lln + 256);
        const float4* l2 = reinterpret_cast<const float4*>(lln + 512);
        const float4* l3 = reinterpret_cast<const float4*>(lln + 768);
        #pragma unroll 8
        for (int m4 = 0; m4 < 64; ++m4) {
            const float4 w = wr[m4];
            a0 += dot4(w, l0[m4]); a1 += dot4(w, l1[m4]);
            a2 += dot4(w, l2[m4]); a3 += dot4(w, l3[m4]);
        }
    }
    const float bj = b1[j];
    const float kInvSqrt2 = 0.70710678118654752f;
    float h0 = a0 + bj, h1 = a1 + bj, h2 = a2 + bj, h3 = a3 + bj;
    lg[0 * 256 + j] = 0.5f * h0 * (1.f + erff(h0 * kInvSqrt2));
    lg[1 * 256 + j] = 0.5f * h1 * (1.f + erff(h1 * kInvSqrt2));
    lg[2 * 256 + j] = 0.5f * h2 * (1.f + erff(h2 * kInvSqrt2));
    lg[3 * 256 + j] = 0.5f * h3 * (1.f + erff(h3 * kInvSqrt2));
    __syncthreads();
    a0 = a1 = a2 = a3 = 0.f;
    {
        const float4* wr = reinterpret_cast<const float4*>(w2 + (size_t)j * 256);
        const float4* l0 = reinterpret_cast<const float4*>(lg);
        const float4* l1 = reinterpret_cast<const float4*>(lg + 256);
        const float4* l2 = reinterpret_cast<const float4*>(lg + 512);
        const float4* l3 = reinterpret_cast<const float4*>(lg + 768);
        #pragma unroll 8
        for (int m4 = 0; m4 < 64; ++m4) {
            const float4 w = wr[m4];
            a0 += dot4(w, l0[m4]); a1 += dot4(w, l1[m4]);
            a2 += dot4(w, l2[m4]); a3 += dot4(w, l3[m4]);
        }
    }
    const float b2j = b2[j];
    affRes[(size_t)(i0 + 0) * 256 + j] = lx[0 * 256 + j] + a0 + b2j;
    affRes[(size_t)(i0 + 1) * 256 + j] = lx[1 * 256 + j] + a1 + b2j;
    affRes[(size_t)(i0 + 2) * 256 + j] = lx[2 * 256 + j] + a2 + b2j;
    affRes[(size_t)(i0 + 3) * 256 + j] = lx[3 * 256 + j] + a3 + b2j;
}

// ---------------------------------------------------------------------------
// Kernel 3a: patch-grid 3x3 conv over 256 channels, split 64-ch per block.
// ---------------------------------------------------------------------------
__global__ __launch_bounds__(256) void k3a_pconv(
        const float* __restrict__ affRes, const float* __restrict__ pw,
        float* __restrict__ part) {
    __shared__ __align__(16) float lpw[576];
    const int b = blockIdx.x >> 2, cc = blockIdx.x & 3;
    const int tid = threadIdx.x;
    for (int idx = tid; idx < 576; idx += 256) {
        const int kk = idx / 64, c = idx & 63;
        lpw[kk * 64 + c] = pw[(size_t)(cc * 64 + c) * 9 + kk];
    }
    __syncthreads();
    if (tid < 196) {
        const int p1 = tid / 14, p2 = tid % 14;
        float s = 0.f;
        #pragma unroll
        for (int ky = 0; ky < 3; ++ky) {
            const int ip1 = p1 + ky - 1;
            if (ip1 < 0 || ip1 > 13) continue;
            #pragma unroll
            for (int kx = 0; kx < 3; ++kx) {
                const int ip2 = p2 + kx - 1;
                if (ip2 < 0 || ip2 > 13) continue;
                const float4* ar = reinterpret_cast<const float4*>(
                    affRes + (size_t)(b * LL + ip1 * 14 + ip2) * 256 + cc * 64);
                const float4* wr = reinterpret_cast<const float4*>(lpw + (ky * 3 + kx) * 64);
                #pragma unroll
                for (int c4 = 0; c4 < 16; ++c4) s += dot4(ar[c4], wr[c4]);
            }
        }
        part[(cc * 8 + b) * 196 + tid] = s;
    }
}

__global__ void k3b_yt(const float* __restrict__ part,
                       const float* __restrict__ pcb, float* __restrict__ out) {
    const int b = blockIdx.x, tid = threadIdx.x;
    if (tid < 196) {
        float s = pcb[0];
        #pragma unroll
        for (int cc = 0; cc < 4; ++cc) s += part[(cc * 8 + b) * 196 + tid];
        out[b * 196 + tid] = s;
    }
}

// ---------------------------------------------------------------------------
// Kernel 4a: SL[btq][l] = (1/32)*dot(syno[q], k-row). One thread per
// (row, D-quarter); 16 acc per thread; block = 64 rows x 4 D-quarters.
// ---------------------------------------------------------------------------
__global__ __launch_bounds__(256) void k4a_new(
        const float* __restrict__ kin, const float* __restrict__ syno,
        float* __restrict__ SL) {
    __shared__ float red[4][64][17];
    const int tid = threadIdx.x, wid = tid >> 6, lane = tid & 63;
    const int dq = __builtin_amdgcn_readfirstlane(wid);
    const int row = blockIdx.x * 64 + lane;          // 0..25087 (392*64 exact)
    const int bt = row / 196, l = row % 196;
    const float* kp = kin + ((size_t)(bt * LP1 + 1 + l)) * DM + dq * 256;
    const float* sp = syno + dq * 256;
    float acc[16];
    #pragma unroll
    for (int q = 0; q < 16; ++q) acc[q] = 0.f;
    #pragma unroll 4
    for (int c = 0; c < 64; ++c) {
        const float4 kv = reinterpret_cast<const float4*>(kp)[c];
        #pragma unroll
        for (int q = 0; q < 16; ++q) {
            const float4 sv = reinterpret_cast<const float4*>(sp + q * 1024)[c];
            acc[q] += dot4(kv, sv);
        }
    }
    #pragma unroll
    for (int q = 0; q < 16; ++q) red[wid][lane][q] = acc[q];
    __syncthreads();
    const int lrow = tid >> 2, q0 = (tid & 3) * 4;
    const int grow = blockIdx.x * 64 + lrow;
    const int bt2 = grow / 196, l2 = grow % 196;
    #pragma unroll
    for (int jj = 0; jj < 4; ++jj) {
        const float s = red[0][lrow][q0 + jj] + red[1][lrow][q0 + jj] +
                        red[2][lrow][q0 + jj] + red[3][lrow][q0 + jj];
        SL[((size_t)bt2 * NS + q0 + jj) * LL + l2] = s * 0.03125f;
    }
}

// Kernel 4b: softmax over l per (b,t,q) + sum over q -> WSUM[b,t,l]
__global__ __launch_bounds__(256) void k4b_softmax(
        const float* __restrict__ SL, float* __restrict__ WSUM) {
    __shared__ float lp[16 * 200];
    const int t = blockIdx.x, b = blockIdx.y;
    const int tid = threadIdx.x;
    const int qq = tid >> 4, j = tid & 15;
    const float* row = SL + (size_t)((b * TT + t) * NS + qq) * LL;
    float v[13];
    float m = -1e30f;
    #pragma unroll
    for (int i = 0; i < 13; ++i) {
        const int l = j + i * 16;
        v[i] = (l < LL) ? row[l] : -1e30f;
        m = fmaxf(m, v[i]);
    }
    #pragma unroll
    for (int msk = 1; msk < 16; msk <<= 1) m = fmaxf(m, __shfl_xor(m, msk, 64));
    float s = 0.f;
    #pragma unroll
    for (int i = 0; i < 13; ++i) {
        const int l = j + i * 16;
        v[i] = (l < LL) ? __expf(v[i] - m) : 0.f;
        s += v[i];
    }
    #pragma unroll
    for (int msk = 1; msk < 16; msk <<= 1) s += __shfl_xor(s, msk, 64);
    const float inv = 1.f / s;
    #pragma unroll
    for (int i = 0; i < 13; ++i) {
        const int l = j + i * 16;
        if (l < LL) lp[qq * 200 + l] = v[i] * inv;
    }
    __syncthreads();
    if (tid < LL) {
        float w = 0.f;
        #pragma unroll
        for (int qi = 0; qi < 16; ++qi) w += lp[qi * 200 + tid];
        WSUM[(size_t)(b * TT + t) * LL + tid] = w;
    }
}

// Kernel 4c: PS[bt][z][:] = sum over 98 rows of WSUM * v  (z-split over l)
__global__ __launch_bounds__(256) void k4c_vsum(
        const float* __restrict__ vin, const float* __restrict__ WSUM,
        float* __restrict__ PS) {
    __shared__ float lw[98];
    const int t = blockIdx.x, b = blockIdx.y, z = blockIdx.z;
    const int tid = threadIdx.x;
    const int bt = b * TT + t;
    if (tid < 98) lw[tid] = WSUM[(size_t)bt * LL + z * 98 + tid];
    __syncthreads();
    float4 acc = make_float4(0.f, 0.f, 0.f, 0.f);
    const float* vb = vin + ((size_t)bt * LP1 + 1 + z * 98) * DM + tid * 4;
    #pragma unroll 4
    for (int l = 0; l < 98; ++l) {
        const float4 v = *reinterpret_cast<const float4*>(vb + (size_t)l * DM);
        const float w = lw[l];
        acc.x += w * v.x; acc.y += w * v.y; acc.z += w * v.z; acc.w += w * v.w;
    }
    *reinterpret_cast<float4*>(PS + ((size_t)bt * 2 + z) * DM + tid * 4) = acc;
}

// Kernel 4d: y_s[b,w] = (1/256) * sum over 32 (t,z) partials
__global__ void k4d_ys(const float* __restrict__ PS, float* __restrict__ out) {
    const int i = blockIdx.x * 256 + threadIdx.x;   // 0..8191
    const int b = i >> 10, w = i & 1023;
    float s = 0.f;
    #pragma unroll
    for (int tz = 0; tz < 32; ++tz) s += PS[((size_t)b * 32 + tz) * DM + w];
    out[1568 + i] = s * (1.f / 256.f);
}

// ---------------------------------------------------------------------------
extern "C" void kernel_launch(void* const* d_in, const int* in_sizes, int n_in,
                              void* d_out, int out_size, void* d_ws, size_t ws_size,
                              hipStream_t stream) {
    const float* q    = (const float*)d_in[0];
    const float* k    = (const float*)d_in[1];
    const float* v    = (const float*)d_in[2];
    const float* syno = (const float*)d_in[3];
    const float* tw   = (const float*)d_in[4];
    const float* tbv  = (const float*)d_in[5];
    const float* lng  = (const float*)d_in[6];
    const float* lnb  = (const float*)d_in[7];
    const float* w1   = (const float*)d_in[8];
    const float* b1   = (const float*)d_in[9];
    const float* w2   = (const float*)d_in[10];
    const float* b2   = (const float*)d_in[11];
    const float* pw   = (const float*)d_in[12];
    const float* pcb  = (const float*)d_in[13];
    float* out = (float*)d_out;

    float* ws = (float*)d_ws;
    float* affRaw = ws;                 // 401408 floats (dead after k2)
    float* affRes = ws + 401408;        // 401408
    float* SL     = ws + 802816;        // 401408
    float* WSUM   = ws + 1204224;       // 25088
    float* part   = ws + 1229312;       // 6272
    float* PS     = ws;                 // 262144, aliases affRaw (k4c after k2)

    // temporal path
    hipLaunchKernelGGL(k1_temporal, dim3(BB * LL), dim3(256), 0, stream,
                       q, k, tw, tbv, affRaw);
    hipLaunchKernelGGL(k2_mlp, dim3(392), dim3(256), 0, stream,
                       affRaw, lng, lnb, w1, b1, w2, b2, affRes);
    hipLaunchKernelGGL(k3a_pconv, dim3(32), dim3(256), 0, stream,
                       affRes, pw, part);
    hipLaunchKernelGGL(k3b_yt, dim3(8), dim3(256), 0, stream, part, pcb, out);
    // spatial path
    hipLaunchKernelGGL(k4a_new, dim3(392), dim3(256), 0, stream, k, syno, SL);
    hipLaunchKernelGGL(k4b_softmax, dim3(16, 8), dim3(256), 0, stream, SL, WSUM);
    hipLaunchKernelGGL(k4c_vsum, dim3(16, 8, 2), dim3(256), 0, stream, v, WSUM, PS);
    hipLaunchKernelGGL(k4d_ys, dim3(32), dim3(256), 0, stream, PS, out);
}

// Round 7
// 219.690 us; speedup vs baseline: 2.2452x; 1.0792x over previous
//
#include <hip/hip_runtime.h>
#include <hip/hip_bf16.h>
#include <math.h>

// Problem constants
#define BB 8
#define TT 16
#define PP 14
#define LL 196      // P*P
#define HH 16
#define DD 64
#define DM 1024     // H*D
#define NS 16
#define T2 256      // T*T
#define LP1 197

using bf16x8 = __attribute__((ext_vector_type(8))) short;
using f32x4  = __attribute__((ext_vector_type(4))) float;

__device__ __forceinline__ float dot4(float4 a, float4 b) {
    return a.x*b.x + a.y*b.y + a.z*b.z + a.w*b.w;
}

// round-to-nearest-even bf16 pack of two finite fp32
__device__ __forceinline__ uint32_t pkbf(float lo, float hi) {
    uint32_t a = __builtin_bit_cast(uint32_t, lo);
    uint32_t b = __builtin_bit_cast(uint32_t, hi);
    a += 0x7FFFu + ((a >> 16) & 1u);
    b += 0x7FFFu + ((b >> 16) & 1u);
    return (a >> 16) | (b & 0xFFFF0000u);
}

// split pair (x,y) into hi/lo bf16 words: x ~= hi.x + lo.x exactly to ~2^-18
__device__ __forceinline__ void split2(float x, float y, uint32_t* h, uint32_t* lo) {
    const uint32_t hh = pkbf(x, y);
    const float hx = __builtin_bit_cast(float, hh << 16);
    const float hy = __builtin_bit_cast(float, hh & 0xFFFF0000u);
    *h = hh;
    *lo = pkbf(x - hx, y - hy);
}

__device__ __forceinline__ void pksplit(float4 p, float4 q, bf16x8& hi, bf16x8& lo) {
    uint32_t uh[4], ul[4];
    split2(p.x, p.y, &uh[0], &ul[0]);
    split2(p.z, p.w, &uh[1], &ul[1]);
    split2(q.x, q.y, &uh[2], &ul[2]);
    split2(q.z, q.w, &uh[3], &ul[3]);
    struct U4 { uint32_t v[4]; } th, tl;
    th.v[0] = uh[0]; th.v[1] = uh[1]; th.v[2] = uh[2]; th.v[3] = uh[3];
    tl.v[0] = ul[0]; tl.v[1] = ul[1]; tl.v[2] = ul[2]; tl.v[3] = ul[3];
    hi = __builtin_bit_cast(bf16x8, th);
    lo = __builtin_bit_cast(bf16x8, tl);
}

// ---------------------------------------------------------------------------
// Kernel 1 (v3): temporal Grams via compensated bf16 MFMA (S = hh + hl + lh),
// direct global->reg fragments (NO LDS staging, NO mid-loop barriers),
// softmax over key frames (max pass), fp32 3x3 conv from [pix][ch] LDS.
// A and B share the same fragment (B = A^T for a Gram), which makes the
// result independent of the A/B k-permutation; S-symmetry makes it
// independent of the C/D orientation. One block per (b, patch l).
// ---------------------------------------------------------------------------
__global__ __launch_bounds__(256) void k1_temporal(
        const float* __restrict__ qin, const float* __restrict__ kin,
        const float* __restrict__ tw,  const float* __restrict__ tbv,
        float* __restrict__ affRaw) {
    __shared__ __align__(16) float lds_c[256 * 36];   // [pix][ch], pad 36
    __shared__ __align__(16) float lds_wf[9 * 32];    // [tap][ch]

    const int bid = blockIdx.x, b = bid / LL, l = bid % LL;
    const int tid = threadIdx.x, wid = tid >> 6, lane = tid & 63;
    const int mrow = lane & 15;            // A-fragment row = frame
    const int g = lane >> 4;               // k-chunk group

    // stage conv weights [tap][ch]  (strided loop: 256 threads < 288 items!)
    for (int i = tid; i < 288; i += 256) {
        const int kk = i >> 5, ch = i & 31;
        lds_wf[kk * 32 + ch] = tw[ch * 9 + kk];
    }

    const size_t rowbase = ((size_t)(b*TT + mrow)*LP1 + 1 + l)*DM + g*8;

    #pragma unroll
    for (int j = 0; j < 4; ++j) {
        #pragma unroll
        for (int hf = 0; hf < 2; ++hf) {
            const int ch = 2*wid + 8*j + hf;        // channel 0..31
            const float* sp2 = (ch < 16) ? qin : kin;
            const float* base = sp2 + rowbase + (size_t)(ch & 15)*DD;
            const float4 a0 = *reinterpret_cast<const float4*>(base);
            const float4 a1 = *reinterpret_cast<const float4*>(base + 4);
            const float4 a2 = *reinterpret_cast<const float4*>(base + 32);
            const float4 a3 = *reinterpret_cast<const float4*>(base + 36);
            bf16x8 h1, l1, h2, l2;
            pksplit(a0, a1, h1, l1);
            pksplit(a2, a3, h2, l2);
            f32x4 acc = {0.f, 0.f, 0.f, 0.f};
            acc = __builtin_amdgcn_mfma_f32_16x16x32_bf16(h1, h1, acc, 0, 0, 0);
            acc = __builtin_amdgcn_mfma_f32_16x16x32_bf16(h1, l1, acc, 0, 0, 0);
            acc = __builtin_amdgcn_mfma_f32_16x16x32_bf16(l1, h1, acc, 0, 0, 0);
            acc = __builtin_amdgcn_mfma_f32_16x16x32_bf16(h2, h2, acc, 0, 0, 0);
            acc = __builtin_amdgcn_mfma_f32_16x16x32_bf16(h2, l2, acc, 0, 0, 0);
            acc = __builtin_amdgcn_mfma_f32_16x16x32_bf16(l2, h2, acc, 0, 0, 0);
            // lane holds S[row=g*4+r][col=lane&15]; softmax over cols (keys)
            const float x0 = acc[0]*0.125f, x1 = acc[1]*0.125f;
            const float x2 = acc[2]*0.125f, x3 = acc[3]*0.125f;
            float m0 = x0, m1 = x1, m2 = x2, m3 = x3;
            #pragma unroll
            for (int msk = 1; msk < 16; msk <<= 1) {
                m0 = fmaxf(m0, __shfl_xor(m0, msk, 64));
                m1 = fmaxf(m1, __shfl_xor(m1, msk, 64));
                m2 = fmaxf(m2, __shfl_xor(m2, msk, 64));
                m3 = fmaxf(m3, __shfl_xor(m3, msk, 64));
            }
            const float e0 = __expf(x0 - m0), e1 = __expf(x1 - m1);
            const float e2 = __expf(x2 - m2), e3 = __expf(x3 - m3);
            float s0 = e0, s1 = e1, s2 = e2, s3 = e3;
            #pragma unroll
            for (int msk = 1; msk < 16; msk <<= 1) {
                s0 += __shfl_xor(s0, msk, 64);
                s1 += __shfl_xor(s1, msk, 64);
                s2 += __shfl_xor(s2, msk, 64);
                s3 += __shfl_xor(s3, msk, 64);
            }
            const int colb = lane & 15;
            lds_c[((g*4 + 0)*16 + colb)*36 + ch] = e0 / s0;
            lds_c[((g*4 + 1)*16 + colb)*36 + ch] = e1 / s1;
            lds_c[((g*4 + 2)*16 + colb)*36 + ch] = e2 / s2;
            lds_c[((g*4 + 3)*16 + colb)*36 + ch] = e3 / s3;
        }
    }
    __syncthreads();

    // 3x3 SAME conv over 32 channels, one output pixel per thread, fp32.
    const int oq = tid >> 4, ok = tid & 15;
    float accv = tbv[0];
    #pragma unroll
    for (int ky = 0; ky < 3; ++ky) {
        const int iq = oq + ky - 1;
        if (iq < 0 || iq > 15) continue;
        #pragma unroll
        for (int kx = 0; kx < 3; ++kx) {
            const int ik = ok + kx - 1;
            if (ik < 0 || ik > 15) continue;
            const float4* dp = reinterpret_cast<const float4*>(lds_c + (iq*16 + ik)*36);
            const float4* wp = reinterpret_cast<const float4*>(lds_wf + (ky*3 + kx)*32);
            #pragma unroll
            for (int c4 = 0; c4 < 8; ++c4) accv += dot4(dp[c4], wp[c4]);
        }
    }
    affRaw[(size_t)bid * T2 + tid] = accv;
}

// ---------------------------------------------------------------------------
// Kernel 2: LayerNorm + MLP (gelu exact) + residual. 4 rows per block.
// ---------------------------------------------------------------------------
__global__ __launch_bounds__(256) void k2_mlp(
        const float* __restrict__ affRaw,
        const float* __restrict__ lng, const float* __restrict__ lnb,
        const float* __restrict__ w1, const float* __restrict__ b1,
        const float* __restrict__ w2, const float* __restrict__ b2,
        float* __restrict__ affRes) {
    __shared__ __align__(16) float lx[4 * 256];
    __shared__ __align__(16) float lln[4 * 256];
    __shared__ __align__(16) float lg[4 * 256];
    const int tid = threadIdx.x;
    const int wave = tid >> 6, lane = tid & 63;
    const int i0 = blockIdx.x * 4;
    {
        const float* xr = affRaw + (size_t)(i0 + wave) * 256;
        float4 x = reinterpret_cast<const float4*>(xr)[lane];
        float sm = x.x + x.y + x.z + x.w;
        float ss = x.x * x.x + x.y * x.y + x.z * x.z + x.w * x.w;
        #pragma unroll
        for (int m = 1; m < 64; m <<= 1) {
            sm += __shfl_xor(sm, m, 64);
            ss += __shfl_xor(ss, m, 64);
        }
        const float mean = sm * (1.f / 256.f);
        const float var = ss * (1.f / 256.f) - mean * mean;
        const float inv = rsqrtf(var + 1e-5f);
        const float4 g4 = reinterpret_cast<const float4*>(lng)[lane];
        const float4 bb = reinterpret_cast<const float4*>(lnb)[lane];
        float4 ln;
        ln.x = (x.x - mean) * inv * g4.x + bb.x;
        ln.y = (x.y - mean) * inv * g4.y + bb.y;
        ln.z = (x.z - mean) * inv * g4.z + bb.z;
        ln.w = (x.w - mean) * inv * g4.w + bb.w;
        reinterpret_cast<float4*>(lx + wave * 256)[lane] = x;
        reinterpret_cast<float4*>(lln + wave * 256)[lane] = ln;
    }
    __syncthreads();
    const int j = tid;
    float a0 = 0.f, a1 = 0.f, a2 = 0.f, a3 = 0.f;
    {
        const float4* wr = reinterpret_cast<const float4*>(w1 + (size_t)j * 256);
        const float4* l0 = reinterpret_cast<const float4*>(lln);
        const float4* l1 = reinterpret_cast<const float4*>(lln + 256);
        const float4* l2 = reinterpret_cast<const float4*>(lln + 512);
        const float4* l3 = reinterpret_cast<const float4*>(lln + 768);
        #pragma unroll 8
        for (int m4 = 0; m4 < 64; ++m4) {
            const float4 w = wr[m4];
            a0 += dot4(w, l0[m4]); a1 += dot4(w, l1[m4]);
            a2 += dot4(w, l2[m4]); a3 += dot4(w, l3[m4]);
        }
    }
    const float bj = b1[j];
    const float kInvSqrt2 = 0.70710678118654752f;
    float h0 = a0 + bj, h1 = a1 + bj, h2 = a2 + bj, h3 = a3 + bj;
    lg[0 * 256 + j] = 0.5f * h0 * (1.f + erff(h0 * kInvSqrt2));
    lg[1 * 256 + j] = 0.5f * h1 * (1.f + erff(h1 * kInvSqrt2));
    lg[2 * 256 + j] = 0.5f * h2 * (1.f + erff(h2 * kInvSqrt2));
    lg[3 * 256 + j] = 0.5f * h3 * (1.f + erff(h3 * kInvSqrt2));
    __syncthreads();
    a0 = a1 = a2 = a3 = 0.f;
    {
        const float4* wr = reinterpret_cast<const float4*>(w2 + (size_t)j * 256);
        const float4* l0 = reinterpret_cast<const float4*>(lg);
        const float4* l1 = reinterpret_cast<const float4*>(lg + 256);
        const float4* l2 = reinterpret_cast<const float4*>(lg + 512);
        const float4* l3 = reinterpret_cast<const float4*>(lg + 768);
        #pragma unroll 8
        for (int m4 = 0; m4 < 64; ++m4) {
            const float4 w = wr[m4];
            a0 += dot4(w, l0[m4]); a1 += dot4(w, l1[m4]);
            a2 += dot4(w, l2[m4]); a3 += dot4(w, l3[m4]);
        }
    }
    const float b2j = b2[j];
    affRes[(size_t)(i0 + 0) * 256 + j] = lx[0 * 256 + j] + a0 + b2j;
    affRes[(size_t)(i0 + 1) * 256 + j] = lx[1 * 256 + j] + a1 + b2j;
    affRes[(size_t)(i0 + 2) * 256 + j] = lx[2 * 256 + j] + a2 + b2j;
    affRes[(size_t)(i0 + 3) * 256 + j] = lx[3 * 256 + j] + a3 + b2j;
}

// ---------------------------------------------------------------------------
// Kernel 3a: patch-grid 3x3 conv over 256 channels, split 64-ch per block.
// ---------------------------------------------------------------------------
__global__ __launch_bounds__(256) void k3a_pconv(
        const float* __restrict__ affRes, const float* __restrict__ pw,
        float* __restrict__ part) {
    __shared__ __align__(16) float lpw[576];
    const int b = blockIdx.x >> 2, cc = blockIdx.x & 3;
    const int tid = threadIdx.x;
    for (int idx = tid; idx < 576; idx += 256) {
        const int kk = idx / 64, c = idx & 63;
        lpw[kk * 64 + c] = pw[(size_t)(cc * 64 + c) * 9 + kk];
    }
    __syncthreads();
    if (tid < 196) {
        const int p1 = tid / 14, p2 = tid % 14;
        float s = 0.f;
        #pragma unroll
        for (int ky = 0; ky < 3; ++ky) {
            const int ip1 = p1 + ky - 1;
            if (ip1 < 0 || ip1 > 13) continue;
            #pragma unroll
            for (int kx = 0; kx < 3; ++kx) {
                const int ip2 = p2 + kx - 1;
                if (ip2 < 0 || ip2 > 13) continue;
                const float4* ar = reinterpret_cast<const float4*>(
                    affRes + (size_t)(b * LL + ip1 * 14 + ip2) * 256 + cc * 64);
                const float4* wr = reinterpret_cast<const float4*>(lpw + (ky * 3 + kx) * 64);
                #pragma unroll
                for (int c4 = 0; c4 < 16; ++c4) s += dot4(ar[c4], wr[c4]);
            }
        }
        part[(cc * 8 + b) * 196 + tid] = s;
    }
}

__global__ void k3b_yt(const float* __restrict__ part,
                       const float* __restrict__ pcb, float* __restrict__ out) {
    const int b = blockIdx.x, tid = threadIdx.x;
    if (tid < 196) {
        float s = pcb[0];
        #pragma unroll
        for (int cc = 0; cc < 4; ++cc) s += part[(cc * 8 + b) * 196 + tid];
        out[b * 196 + tid] = s;
    }
}

// ---------------------------------------------------------------------------
// Kernel 4a: SL[btq][l] = (1/32)*dot(syno[q], k-row). One thread per
// (row, D-quarter); 16 acc per thread; block = 64 rows x 4 D-quarters.
// ---------------------------------------------------------------------------
__global__ __launch_bounds__(256) void k4a_new(
        const float* __restrict__ kin, const float* __restrict__ syno,
        float* __restrict__ SL) {
    __shared__ float red[4][64][17];
    const int tid = threadIdx.x, wid = tid >> 6, lane = tid & 63;
    const int dq = __builtin_amdgcn_readfirstlane(wid);
    const int row = blockIdx.x * 64 + lane;          // 0..25087 (392*64 exact)
    const int bt = row / 196, l = row % 196;
    const float* kp = kin + ((size_t)(bt * LP1 + 1 + l)) * DM + dq * 256;
    const float* sp = syno + dq * 256;
    float acc[16];
    #pragma unroll
    for (int q = 0; q < 16; ++q) acc[q] = 0.f;
    #pragma unroll 4
    for (int c = 0; c < 64; ++c) {
        const float4 kv = reinterpret_cast<const float4*>(kp)[c];
        #pragma unroll
        for (int q = 0; q < 16; ++q) {
            const float4 sv = reinterpret_cast<const float4*>(sp + q * 1024)[c];
            acc[q] += dot4(kv, sv);
        }
    }
    #pragma unroll
    for (int q = 0; q < 16; ++q) red[wid][lane][q] = acc[q];
    __syncthreads();
    const int lrow = tid >> 2, q0 = (tid & 3) * 4;
    const int grow = blockIdx.x * 64 + lrow;
    const int bt2 = grow / 196, l2 = grow % 196;
    #pragma unroll
    for (int jj = 0; jj < 4; ++jj) {
        const float s = red[0][lrow][q0 + jj] + red[1][lrow][q0 + jj] +
                        red[2][lrow][q0 + jj] + red[3][lrow][q0 + jj];
        SL[((size_t)bt2 * NS + q0 + jj) * LL + l2] = s * 0.03125f;
    }
}

// Kernel 4b: softmax over l per (b,t,q) + sum over q -> WSUM[b,t,l]
__global__ __launch_bounds__(256) void k4b_softmax(
        const float* __restrict__ SL, float* __restrict__ WSUM) {
    __shared__ float lp[16 * 200];
    const int t = blockIdx.x, b = blockIdx.y;
    const int tid = threadIdx.x;
    const int qq = tid >> 4, j = tid & 15;
    const float* row = SL + (size_t)((b * TT + t) * NS + qq) * LL;
    float v[13];
    float m = -1e30f;
    #pragma unroll
    for (int i = 0; i < 13; ++i) {
        const int l = j + i * 16;
        v[i] = (l < LL) ? row[l] : -1e30f;
        m = fmaxf(m, v[i]);
    }
    #pragma unroll
    for (int msk = 1; msk < 16; msk <<= 1) m = fmaxf(m, __shfl_xor(m, msk, 64));
    float s = 0.f;
    #pragma unroll
    for (int i = 0; i < 13; ++i) {
        const int l = j + i * 16;
        v[i] = (l < LL) ? __expf(v[i] - m) : 0.f;
        s += v[i];
    }
    #pragma unroll
    for (int msk = 1; msk < 16; msk <<= 1) s += __shfl_xor(s, msk, 64);
    const float inv = 1.f / s;
    #pragma unroll
    for (int i = 0; i < 13; ++i) {
        const int l = j + i * 16;
        if (l < LL) lp[qq * 200 + l] = v[i] * inv;
    }
    __syncthreads();
    if (tid < LL) {
        float w = 0.f;
        #pragma unroll
        for (int qi = 0; qi < 16; ++qi) w += lp[qi * 200 + tid];
        WSUM[(size_t)(b * TT + t) * LL + tid] = w;
    }
}

// Kernel 4c: PS[bt][z][:] = sum over 98 rows of WSUM * v  (z-split over l)
__global__ __launch_bounds__(256) void k4c_vsum(
        const float* __restrict__ vin, const float* __restrict__ WSUM,
        float* __restrict__ PS) {
    __shared__ float lw[98];
    const int t = blockIdx.x, b = blockIdx.y, z = blockIdx.z;
    const int tid = threadIdx.x;
    const int bt = b * TT + t;
    if (tid < 98) lw[tid] = WSUM[(size_t)bt * LL + z * 98 + tid];
    __syncthreads();
    float4 acc = make_float4(0.f, 0.f, 0.f, 0.f);
    const float* vb = vin + ((size_t)bt * LP1 + 1 + z * 98) * DM + tid * 4;
    #pragma unroll 4
    for (int l = 0; l < 98; ++l) {
        const float4 v = *reinterpret_cast<const float4*>(vb + (size_t)l * DM);
        const float w = lw[l];
        acc.x += w * v.x; acc.y += w * v.y; acc.z += w * v.z; acc.w += w * v.w;
    }
    *reinterpret_cast<float4*>(PS + ((size_t)bt * 2 + z) * DM + tid * 4) = acc;
}

// Kernel 4d: y_s[b,w] = (1/256) * sum over 32 (t,z) partials
__global__ void k4d_ys(const float* __restrict__ PS, float* __restrict__ out) {
    const int i = blockIdx.x * 256 + threadIdx.x;   // 0..8191
    const int b = i >> 10, w = i & 1023;
    float s = 0.f;
    #pragma unroll
    for (int tz = 0; tz < 32; ++tz) s += PS[((size_t)b * 32 + tz) * DM + w];
    out[1568 + i] = s * (1.f / 256.f);
}

// ---------------------------------------------------------------------------
extern "C" void kernel_launch(void* const* d_in, const int* in_sizes, int n_in,
                              void* d_out, int out_size, void* d_ws, size_t ws_size,
                              hipStream_t stream) {
    const float* q    = (const float*)d_in[0];
    const float* k    = (const float*)d_in[1];
    const float* v    = (const float*)d_in[2];
    const float* syno = (const float*)d_in[3];
    const float* tw   = (const float*)d_in[4];
    const float* tbv  = (const float*)d_in[5];
    const float* lng  = (const float*)d_in[6];
    const float* lnb  = (const float*)d_in[7];
    const float* w1   = (const float*)d_in[8];
    const float* b1   = (const float*)d_in[9];
    const float* w2   = (const float*)d_in[10];
    const float* b2   = (const float*)d_in[11];
    const float* pw   = (const float*)d_in[12];
    const float* pcb  = (const float*)d_in[13];
    float* out = (float*)d_out;

    float* ws = (float*)d_ws;
    float* affRaw = ws;                 // 401408 floats (dead after k2)
    float* affRes = ws + 401408;        // 401408
    float* SL     = ws + 802816;        // 401408
    float* WSUM   = ws + 1204224;       // 25088
    float* part   = ws + 1229312;       // 6272
    float* PS     = ws;                 // 262144, aliases affRaw (k4c after k2)

    // temporal path
    hipLaunchKernelGGL(k1_temporal, dim3(BB * LL), dim3(256), 0, stream,
                       q, k, tw, tbv, affRaw);
    hipLaunchKernelGGL(k2_mlp, dim3(392), dim3(256), 0, stream,
                       affRaw, lng, lnb, w1, b1, w2, b2, affRes);
    hipLaunchKernelGGL(k3a_pconv, dim3(32), dim3(256), 0, stream,
                       affRes, pw, part);
    hipLaunchKernelGGL(k3b_yt, dim3(8), dim3(256), 0, stream, part, pcb, out);
    // spatial path
    hipLaunchKernelGGL(k4a_new, dim3(392), dim3(256), 0, stream, k, syno, SL);
    hipLaunchKernelGGL(k4b_softmax, dim3(16, 8), dim3(256), 0, stream, SL, WSUM);
    hipLaunchKernelGGL(k4c_vsum, dim3(16, 8, 2), dim3(256), 0, stream, v, WSUM, PS);
    hipLaunchKernelGGL(k4d_ys, dim3(32), dim3(256), 0, stream, PS, out);
}

// Round 8
// 157.768 us; speedup vs baseline: 3.1264x; 1.3925x over previous
//
#include <hip/hip_runtime.h>
#include <hip/hip_bf16.h>
#include <math.h>

// Problem constants
#define BB 8
#define TT 16
#define PP 14
#define LL 196      // P*P
#define HH 16
#define DD 64
#define DM 1024     // H*D
#define NS 16
#define T2 256      // T*T
#define LP1 197

using bf16x8 = __attribute__((ext_vector_type(8))) short;
using f32x4  = __attribute__((ext_vector_type(4))) float;

__device__ __forceinline__ float dot4(float4 a, float4 b) {
    return a.x*b.x + a.y*b.y + a.z*b.z + a.w*b.w;
}

// round-to-nearest-even bf16 pack of two finite fp32
__device__ __forceinline__ uint32_t pkbf(float lo, float hi) {
    uint32_t a = __builtin_bit_cast(uint32_t, lo);
    uint32_t b = __builtin_bit_cast(uint32_t, hi);
    a += 0x7FFFu + ((a >> 16) & 1u);
    b += 0x7FFFu + ((b >> 16) & 1u);
    return (a >> 16) | (b & 0xFFFF0000u);
}

// split pair (x,y) into hi/lo bf16 words: x ~= hi.x + lo.x exactly to ~2^-18
__device__ __forceinline__ void split2(float x, float y, uint32_t* h, uint32_t* lo) {
    const uint32_t hh = pkbf(x, y);
    const float hx = __builtin_bit_cast(float, hh << 16);
    const float hy = __builtin_bit_cast(float, hh & 0xFFFF0000u);
    *h = hh;
    *lo = pkbf(x - hx, y - hy);
}

__device__ __forceinline__ void pksplit(float4 p, float4 q, bf16x8& hi, bf16x8& lo) {
    uint32_t uh[4], ul[4];
    split2(p.x, p.y, &uh[0], &ul[0]);
    split2(p.z, p.w, &uh[1], &ul[1]);
    split2(q.x, q.y, &uh[2], &ul[2]);
    split2(q.z, q.w, &uh[3], &ul[3]);
    struct U4 { uint32_t v[4]; } th, tl;
    th.v[0] = uh[0]; th.v[1] = uh[1]; th.v[2] = uh[2]; th.v[3] = uh[3];
    tl.v[0] = ul[0]; tl.v[1] = ul[1]; tl.v[2] = ul[2]; tl.v[3] = ul[3];
    hi = __builtin_bit_cast(bf16x8, th);
    lo = __builtin_bit_cast(bf16x8, tl);
}

// ---------------------------------------------------------------------------
// Kernel 0: pre-split syno (16x1024 fp32) into hi/lo bf16 pair-words so k1
// can load B-fragments directly. 8192 pairs.
// ---------------------------------------------------------------------------
__global__ __launch_bounds__(256) void kprep(
        const float* __restrict__ syno,
        uint32_t* __restrict__ synoHi, uint32_t* __restrict__ synoLo) {
    const int i = blockIdx.x * 256 + threadIdx.x;   // 0..8191
    const float x = syno[2 * i], y = syno[2 * i + 1];
    uint32_t h, lo;
    split2(x, y, &h, &lo);
    synoHi[i] = h;
    synoLo[i] = lo;
}

// ---------------------------------------------------------------------------
// Kernel 1 (v4): temporal Grams via compensated bf16 MFMA + FUSED spatial
// logits. The k-channel fragments (h1,l1,h2,l2) already in registers are
// reused against pre-split syno B-fragments (lane&15 = q, same k-indexing
// as A => shared-permutation cancellation). acc_sl[r] = SL[t=g*4+r][q].
// Cross-wave partial (4 heads/wave) reduced via sl_part. One block/(b,l).
// ---------------------------------------------------------------------------
__global__ __launch_bounds__(256) void k1_temporal(
        const float* __restrict__ qin, const float* __restrict__ kin,
        const float* __restrict__ tw,  const float* __restrict__ tbv,
        const uint32_t* __restrict__ synoHi, const uint32_t* __restrict__ synoLo,
        float* __restrict__ affRaw, float* __restrict__ SLout) {
    __shared__ __align__(16) float lds_c[256 * 36];   // [pix][ch], pad 36
    __shared__ __align__(16) float lds_wf[9 * 32];    // [tap][ch]
    __shared__ __align__(16) float sl_part[4][16][16];

    const int bid = blockIdx.x, b = bid / LL, l = bid % LL;
    const int tid = threadIdx.x, wid = tid >> 6, lane = tid & 63;
    const int mrow = lane & 15;            // A-fragment row = frame
    const int g = lane >> 4;               // k-chunk group

    // stage conv weights [tap][ch]
    for (int i = tid; i < 288; i += 256) {
        const int kk = i >> 5, ch = i & 31;
        lds_wf[kk * 32 + ch] = tw[ch * 9 + kk];
    }

    const size_t rowbase = ((size_t)(b*TT + mrow)*LP1 + 1 + l)*DM + g*8;
    f32x4 acc_sl = {0.f, 0.f, 0.f, 0.f};

    #pragma unroll
    for (int j = 0; j < 4; ++j) {
        #pragma unroll
        for (int hf = 0; hf < 2; ++hf) {
            const int ch = 2*wid + 8*j + hf;        // channel 0..31
            const float* sp2 = (ch < 16) ? qin : kin;
            const float* base = sp2 + rowbase + (size_t)(ch & 15)*DD;
            const float4 a0 = *reinterpret_cast<const float4*>(base);
            const float4 a1 = *reinterpret_cast<const float4*>(base + 4);
            const float4 a2 = *reinterpret_cast<const float4*>(base + 32);
            const float4 a3 = *reinterpret_cast<const float4*>(base + 36);
            bf16x8 h1, l1, h2, l2;
            pksplit(a0, a1, h1, l1);
            pksplit(a2, a3, h2, l2);
            f32x4 acc = {0.f, 0.f, 0.f, 0.f};
            acc = __builtin_amdgcn_mfma_f32_16x16x32_bf16(h1, h1, acc, 0, 0, 0);
            acc = __builtin_amdgcn_mfma_f32_16x16x32_bf16(h1, l1, acc, 0, 0, 0);
            acc = __builtin_amdgcn_mfma_f32_16x16x32_bf16(l1, h1, acc, 0, 0, 0);
            acc = __builtin_amdgcn_mfma_f32_16x16x32_bf16(h2, h2, acc, 0, 0, 0);
            acc = __builtin_amdgcn_mfma_f32_16x16x32_bf16(h2, l2, acc, 0, 0, 0);
            acc = __builtin_amdgcn_mfma_f32_16x16x32_bf16(l2, h2, acc, 0, 0, 0);
            // fused spatial logits: k channels only (ch>=16), wave-uniform branch
            if (ch >= 16) {
                const int off = (lane & 15) * 512 + (ch - 16) * 32 + g * 4;
                const bf16x8 sh1 = *reinterpret_cast<const bf16x8*>(synoHi + off);
                const bf16x8 sl1 = *reinterpret_cast<const bf16x8*>(synoLo + off);
                const bf16x8 sh2 = *reinterpret_cast<const bf16x8*>(synoHi + off + 16);
                const bf16x8 sl2 = *reinterpret_cast<const bf16x8*>(synoLo + off + 16);
                acc_sl = __builtin_amdgcn_mfma_f32_16x16x32_bf16(h1, sh1, acc_sl, 0, 0, 0);
                acc_sl = __builtin_amdgcn_mfma_f32_16x16x32_bf16(h1, sl1, acc_sl, 0, 0, 0);
                acc_sl = __builtin_amdgcn_mfma_f32_16x16x32_bf16(l1, sh1, acc_sl, 0, 0, 0);
                acc_sl = __builtin_amdgcn_mfma_f32_16x16x32_bf16(h2, sh2, acc_sl, 0, 0, 0);
                acc_sl = __builtin_amdgcn_mfma_f32_16x16x32_bf16(h2, sl2, acc_sl, 0, 0, 0);
                acc_sl = __builtin_amdgcn_mfma_f32_16x16x32_bf16(l2, sh2, acc_sl, 0, 0, 0);
            }
            // lane holds S[row=g*4+r][col=lane&15]; softmax over cols (keys)
            const float x0 = acc[0]*0.125f, x1 = acc[1]*0.125f;
            const float x2 = acc[2]*0.125f, x3 = acc[3]*0.125f;
            float m0 = x0, m1 = x1, m2 = x2, m3 = x3;
            #pragma unroll
            for (int msk = 1; msk < 16; msk <<= 1) {
                m0 = fmaxf(m0, __shfl_xor(m0, msk, 64));
                m1 = fmaxf(m1, __shfl_xor(m1, msk, 64));
                m2 = fmaxf(m2, __shfl_xor(m2, msk, 64));
                m3 = fmaxf(m3, __shfl_xor(m3, msk, 64));
            }
            const float e0 = __expf(x0 - m0), e1 = __expf(x1 - m1);
            const float e2 = __expf(x2 - m2), e3 = __expf(x3 - m3);
            float s0 = e0, s1 = e1, s2 = e2, s3 = e3;
            #pragma unroll
            for (int msk = 1; msk < 16; msk <<= 1) {
                s0 += __shfl_xor(s0, msk, 64);
                s1 += __shfl_xor(s1, msk, 64);
                s2 += __shfl_xor(s2, msk, 64);
                s3 += __shfl_xor(s3, msk, 64);
            }
            const int colb = lane & 15;
            lds_c[((g*4 + 0)*16 + colb)*36 + ch] = e0 / s0;
            lds_c[((g*4 + 1)*16 + colb)*36 + ch] = e1 / s1;
            lds_c[((g*4 + 2)*16 + colb)*36 + ch] = e2 / s2;
            lds_c[((g*4 + 3)*16 + colb)*36 + ch] = e3 / s3;
        }
    }
    // per-wave SL partial (4 heads = 256 dims each)
    #pragma unroll
    for (int r = 0; r < 4; ++r)
        sl_part[wid][g * 4 + r][lane & 15] = acc_sl[r];
    __syncthreads();

    // 3x3 SAME conv over 32 channels, one output pixel per thread, fp32.
    const int oq = tid >> 4, ok = tid & 15;
    float accv = tbv[0];
    #pragma unroll
    for (int ky = 0; ky < 3; ++ky) {
        const int iq = oq + ky - 1;
        if (iq < 0 || iq > 15) continue;
        #pragma unroll
        for (int kx = 0; kx < 3; ++kx) {
            const int ik = ok + kx - 1;
            if (ik < 0 || ik > 15) continue;
            const float4* dp = reinterpret_cast<const float4*>(lds_c + (iq*16 + ik)*36);
            const float4* wp = reinterpret_cast<const float4*>(lds_wf + (ky*3 + kx)*32);
            #pragma unroll
            for (int c4 = 0; c4 < 8; ++c4) accv += dot4(dp[c4], wp[c4]);
        }
    }
    affRaw[(size_t)bid * T2 + tid] = accv;

    // SL reduce over the 4 waves + scaled write: thread = (t, q)
    {
        const int t = tid >> 4, qq = tid & 15;
        const float s = sl_part[0][t][qq] + sl_part[1][t][qq] +
                        sl_part[2][t][qq] + sl_part[3][t][qq];
        SLout[((size_t)(b * TT + t) * NS + qq) * LL + l] = s * 0.03125f;
    }
}

// ---------------------------------------------------------------------------
// Kernel 2: LayerNorm + MLP (gelu exact) + residual. 4 rows per block.
// ---------------------------------------------------------------------------
__global__ __launch_bounds__(256) void k2_mlp(
        const float* __restrict__ affRaw,
        const float* __restrict__ lng, const float* __restrict__ lnb,
        const float* __restrict__ w1, const float* __restrict__ b1,
        const float* __restrict__ w2, const float* __restrict__ b2,
        float* __restrict__ affRes) {
    __shared__ __align__(16) float lx[4 * 256];
    __shared__ __align__(16) float lln[4 * 256];
    __shared__ __align__(16) float lg[4 * 256];
    const int tid = threadIdx.x;
    const int wave = tid >> 6, lane = tid & 63;
    const int i0 = blockIdx.x * 4;
    {
        const float* xr = affRaw + (size_t)(i0 + wave) * 256;
        float4 x = reinterpret_cast<const float4*>(xr)[lane];
        float sm = x.x + x.y + x.z + x.w;
        float ss = x.x * x.x + x.y * x.y + x.z * x.z + x.w * x.w;
        #pragma unroll
        for (int m = 1; m < 64; m <<= 1) {
            sm += __shfl_xor(sm, m, 64);
            ss += __shfl_xor(ss, m, 64);
        }
        const float mean = sm * (1.f / 256.f);
        const float var = ss * (1.f / 256.f) - mean * mean;
        const float inv = rsqrtf(var + 1e-5f);
        const float4 g4 = reinterpret_cast<const float4*>(lng)[lane];
        const float4 bb = reinterpret_cast<const float4*>(lnb)[lane];
        float4 ln;
        ln.x = (x.x - mean) * inv * g4.x + bb.x;
        ln.y = (x.y - mean) * inv * g4.y + bb.y;
        ln.z = (x.z - mean) * inv * g4.z + bb.z;
        ln.w = (x.w - mean) * inv * g4.w + bb.w;
        reinterpret_cast<float4*>(lx + wave * 256)[lane] = x;
        reinterpret_cast<float4*>(lln + wave * 256)[lane] = ln;
    }
    __syncthreads();
    const int j = tid;
    float a0 = 0.f, a1 = 0.f, a2 = 0.f, a3 = 0.f;
    {
        const float4* wr = reinterpret_cast<const float4*>(w1 + (size_t)j * 256);
        const float4* l0 = reinterpret_cast<const float4*>(lln);
        const float4* l1 = reinterpret_cast<const float4*>(lln + 256);
        const float4* l2 = reinterpret_cast<const float4*>(lln + 512);
        const float4* l3 = reinterpret_cast<const float4*>(lln + 768);
        #pragma unroll 8
        for (int m4 = 0; m4 < 64; ++m4) {
            const float4 w = wr[m4];
            a0 += dot4(w, l0[m4]); a1 += dot4(w, l1[m4]);
            a2 += dot4(w, l2[m4]); a3 += dot4(w, l3[m4]);
        }
    }
    const float bj = b1[j];
    const float kInvSqrt2 = 0.70710678118654752f;
    float h0 = a0 + bj, h1 = a1 + bj, h2 = a2 + bj, h3 = a3 + bj;
    lg[0 * 256 + j] = 0.5f * h0 * (1.f + erff(h0 * kInvSqrt2));
    lg[1 * 256 + j] = 0.5f * h1 * (1.f + erff(h1 * kInvSqrt2));
    lg[2 * 256 + j] = 0.5f * h2 * (1.f + erff(h2 * kInvSqrt2));
    lg[3 * 256 + j] = 0.5f * h3 * (1.f + erff(h3 * kInvSqrt2));
    __syncthreads();
    a0 = a1 = a2 = a3 = 0.f;
    {
        const float4* wr = reinterpret_cast<const float4*>(w2 + (size_t)j * 256);
        const float4* l0 = reinterpret_cast<const float4*>(lg);
        const float4* l1 = reinterpret_cast<const float4*>(lg + 256);
        const float4* l2 = reinterpret_cast<const float4*>(lg + 512);
        const float4* l3 = reinterpret_cast<const float4*>(lg + 768);
        #pragma unroll 8
        for (int m4 = 0; m4 < 64; ++m4) {
            const float4 w = wr[m4];
            a0 += dot4(w, l0[m4]); a1 += dot4(w, l1[m4]);
            a2 += dot4(w, l2[m4]); a3 += dot4(w, l3[m4]);
        }
    }
    const float b2j = b2[j];
    affRes[(size_t)(i0 + 0) * 256 + j] = lx[0 * 256 + j] + a0 + b2j;
    affRes[(size_t)(i0 + 1) * 256 + j] = lx[1 * 256 + j] + a1 + b2j;
    affRes[(size_t)(i0 + 2) * 256 + j] = lx[2 * 256 + j] + a2 + b2j;
    affRes[(size_t)(i0 + 3) * 256 + j] = lx[3 * 256 + j] + a3 + b2j;
}

// ---------------------------------------------------------------------------
// Kernel 3a: patch-grid 3x3 conv over 256 channels, split 64-ch per block.
// ---------------------------------------------------------------------------
__global__ __launch_bounds__(256) void k3a_pconv(
        const float* __restrict__ affRes, const float* __restrict__ pw,
        float* __restrict__ part) {
    __shared__ __align__(16) float lpw[576];
    const int b = blockIdx.x >> 2, cc = blockIdx.x & 3;
    const int tid = threadIdx.x;
    for (int idx = tid; idx < 576; idx += 256) {
        const int kk = idx / 64, c = idx & 63;
        lpw[kk * 64 + c] = pw[(size_t)(cc * 64 + c) * 9 + kk];
    }
    __syncthreads();
    if (tid < 196) {
        const int p1 = tid / 14, p2 = tid % 14;
        float s = 0.f;
        #pragma unroll
        for (int ky = 0; ky < 3; ++ky) {
            const int ip1 = p1 + ky - 1;
            if (ip1 < 0 || ip1 > 13) continue;
            #pragma unroll
            for (int kx = 0; kx < 3; ++kx) {
                const int ip2 = p2 + kx - 1;
                if (ip2 < 0 || ip2 > 13) continue;
                const float4* ar = reinterpret_cast<const float4*>(
                    affRes + (size_t)(b * LL + ip1 * 14 + ip2) * 256 + cc * 64);
                const float4* wr = reinterpret_cast<const float4*>(lpw + (ky * 3 + kx) * 64);
                #pragma unroll
                for (int c4 = 0; c4 < 16; ++c4) s += dot4(ar[c4], wr[c4]);
            }
        }
        part[(cc * 8 + b) * 196 + tid] = s;
    }
}

__global__ void k3b_yt(const float* __restrict__ part,
                       const float* __restrict__ pcb, float* __restrict__ out) {
    const int b = blockIdx.x, tid = threadIdx.x;
    if (tid < 196) {
        float s = pcb[0];
        #pragma unroll
        for (int cc = 0; cc < 4; ++cc) s += part[(cc * 8 + b) * 196 + tid];
        out[b * 196 + tid] = s;
    }
}

// Kernel 4b: softmax over l per (b,t,q) + sum over q -> WSUM[b,t,l]
__global__ __launch_bounds__(256) void k4b_softmax(
        const float* __restrict__ SL, float* __restrict__ WSUM) {
    __shared__ float lp[16 * 200];
    const int t = blockIdx.x, b = blockIdx.y;
    const int tid = threadIdx.x;
    const int qq = tid >> 4, j = tid & 15;
    const float* row = SL + (size_t)((b * TT + t) * NS + qq) * LL;
    float v[13];
    float m = -1e30f;
    #pragma unroll
    for (int i = 0; i < 13; ++i) {
        const int l = j + i * 16;
        v[i] = (l < LL) ? row[l] : -1e30f;
        m = fmaxf(m, v[i]);
    }
    #pragma unroll
    for (int msk = 1; msk < 16; msk <<= 1) m = fmaxf(m, __shfl_xor(m, msk, 64));
    float s = 0.f;
    #pragma unroll
    for (int i = 0; i < 13; ++i) {
        const int l = j + i * 16;
        v[i] = (l < LL) ? __expf(v[i] - m) : 0.f;
        s += v[i];
    }
    #pragma unroll
    for (int msk = 1; msk < 16; msk <<= 1) s += __shfl_xor(s, msk, 64);
    const float inv = 1.f / s;
    #pragma unroll
    for (int i = 0; i < 13; ++i) {
        const int l = j + i * 16;
        if (l < LL) lp[qq * 200 + l] = v[i] * inv;
    }
    __syncthreads();
    if (tid < LL) {
        float w = 0.f;
        #pragma unroll
        for (int qi = 0; qi < 16; ++qi) w += lp[qi * 200 + tid];
        WSUM[(size_t)(b * TT + t) * LL + tid] = w;
    }
}

// Kernel 4c: PS[bt][z][:] = sum over 98 rows of WSUM * v  (z-split over l)
__global__ __launch_bounds__(256) void k4c_vsum(
        const float* __restrict__ vin, const float* __restrict__ WSUM,
        float* __restrict__ PS) {
    __shared__ float lw[98];
    const int t = blockIdx.x, b = blockIdx.y, z = blockIdx.z;
    const int tid = threadIdx.x;
    const int bt = b * TT + t;
    if (tid < 98) lw[tid] = WSUM[(size_t)bt * LL + z * 98 + tid];
    __syncthreads();
    float4 acc = make_float4(0.f, 0.f, 0.f, 0.f);
    const float* vb = vin + ((size_t)bt * LP1 + 1 + z * 98) * DM + tid * 4;
    #pragma unroll 4
    for (int l = 0; l < 98; ++l) {
        const float4 v = *reinterpret_cast<const float4*>(vb + (size_t)l * DM);
        const float w = lw[l];
        acc.x += w * v.x; acc.y += w * v.y; acc.z += w * v.z; acc.w += w * v.w;
    }
    *reinterpret_cast<float4*>(PS + ((size_t)bt * 2 + z) * DM + tid * 4) = acc;
}

// Kernel 4d: y_s[b,w] = (1/256) * sum over 32 (t,z) partials
__global__ void k4d_ys(const float* __restrict__ PS, float* __restrict__ out) {
    const int i = blockIdx.x * 256 + threadIdx.x;   // 0..8191
    const int b = i >> 10, w = i & 1023;
    float s = 0.f;
    #pragma unroll
    for (int tz = 0; tz < 32; ++tz) s += PS[((size_t)b * 32 + tz) * DM + w];
    out[1568 + i] = s * (1.f / 256.f);
}

// ---------------------------------------------------------------------------
extern "C" void kernel_launch(void* const* d_in, const int* in_sizes, int n_in,
                              void* d_out, int out_size, void* d_ws, size_t ws_size,
                              hipStream_t stream) {
    const float* q    = (const float*)d_in[0];
    const float* k    = (const float*)d_in[1];
    const float* v    = (const float*)d_in[2];
    const float* syno = (const float*)d_in[3];
    const float* tw   = (const float*)d_in[4];
    const float* tbv  = (const float*)d_in[5];
    const float* lng  = (const float*)d_in[6];
    const float* lnb  = (const float*)d_in[7];
    const float* w1   = (const float*)d_in[8];
    const float* b1   = (const float*)d_in[9];
    const float* w2   = (const float*)d_in[10];
    const float* b2   = (const float*)d_in[11];
    const float* pw   = (const float*)d_in[12];
    const float* pcb  = (const float*)d_in[13];
    float* out = (float*)d_out;

    float* ws = (float*)d_ws;
    float* affRaw = ws;                 // 401408 floats (dead after k2)
    float* affRes = ws + 401408;        // 401408
    float* SL     = ws + 802816;        // 401408
    float* WSUM   = ws + 1204224;       // 25088
    float* part   = ws + 1229312;       // 6272
    uint32_t* synoHi = (uint32_t*)(ws + 1235584);   // 8192 u32
    uint32_t* synoLo = (uint32_t*)(ws + 1243776);   // 8192 u32
    float* PS     = ws;                 // 262144, aliases affRaw (k4c after k2)

    // syno pre-split (hi/lo bf16)
    hipLaunchKernelGGL(kprep, dim3(32), dim3(256), 0, stream, syno, synoHi, synoLo);
    // temporal path + fused spatial logits
    hipLaunchKernelGGL(k1_temporal, dim3(BB * LL), dim3(256), 0, stream,
                       q, k, tw, tbv, synoHi, synoLo, affRaw, SL);
    hipLaunchKernelGGL(k2_mlp, dim3(392), dim3(256), 0, stream,
                       affRaw, lng, lnb, w1, b1, w2, b2, affRes);
    hipLaunchKernelGGL(k3a_pconv, dim3(32), dim3(256), 0, stream,
                       affRes, pw, part);
    hipLaunchKernelGGL(k3b_yt, dim3(8), dim3(256), 0, stream, part, pcb, out);
    // spatial path (k4a fused into k1)
    hipLaunchKernelGGL(k4b_softmax, dim3(16, 8), dim3(256), 0, stream, SL, WSUM);
    hipLaunchKernelGGL(k4c_vsum, dim3(16, 8, 2), dim3(256), 0, stream, v, WSUM, PS);
    hipLaunchKernelGGL(k4d_ys, dim3(32), dim3(256), 0, stream, PS, out);
}

// Round 9
// 149.292 us; speedup vs baseline: 3.3039x; 1.0568x over previous
//
#include <hip/hip_runtime.h>
#include <hip/hip_bf16.h>
#include <math.h>

// Problem constants
#define BB 8
#define TT 16
#define PP 14
#define LL 196      // P*P
#define HH 16
#define DD 64
#define DM 1024     // H*D
#define NS 16
#define T2 256      // T*T
#define LP1 197

using bf16x8 = __attribute__((ext_vector_type(8))) short;
using f32x4  = __attribute__((ext_vector_type(4))) float;

__device__ __forceinline__ float dot4(float4 a, float4 b) {
    return a.x*b.x + a.y*b.y + a.z*b.z + a.w*b.w;
}

// round-to-nearest-even bf16 pack of two finite fp32
__device__ __forceinline__ uint32_t pkbf(float lo, float hi) {
    uint32_t a = __builtin_bit_cast(uint32_t, lo);
    uint32_t b = __builtin_bit_cast(uint32_t, hi);
    a += 0x7FFFu + ((a >> 16) & 1u);
    b += 0x7FFFu + ((b >> 16) & 1u);
    return (a >> 16) | (b & 0xFFFF0000u);
}

// split pair (x,y) into hi/lo bf16 words: x ~= hi.x + lo.x exactly to ~2^-18
__device__ __forceinline__ void split2(float x, float y, uint32_t* h, uint32_t* lo) {
    const uint32_t hh = pkbf(x, y);
    const float hx = __builtin_bit_cast(float, hh << 16);
    const float hy = __builtin_bit_cast(float, hh & 0xFFFF0000u);
    *h = hh;
    *lo = pkbf(x - hx, y - hy);
}

__device__ __forceinline__ void pksplit(float4 p, float4 q, bf16x8& hi, bf16x8& lo) {
    uint32_t uh[4], ul[4];
    split2(p.x, p.y, &uh[0], &ul[0]);
    split2(p.z, p.w, &uh[1], &ul[1]);
    split2(q.x, q.y, &uh[2], &ul[2]);
    split2(q.z, q.w, &uh[3], &ul[3]);
    struct U4 { uint32_t v[4]; } th, tl;
    th.v[0] = uh[0]; th.v[1] = uh[1]; th.v[2] = uh[2]; th.v[3] = uh[3];
    tl.v[0] = ul[0]; tl.v[1] = ul[1]; tl.v[2] = ul[2]; tl.v[3] = ul[3];
    hi = __builtin_bit_cast(bf16x8, th);
    lo = __builtin_bit_cast(bf16x8, tl);
}

// ---------------------------------------------------------------------------
// Kernel 0: pre-split syno (16x1024 fp32) into hi/lo bf16 pair-words.
// ---------------------------------------------------------------------------
__global__ __launch_bounds__(256) void kprep(
        const float* __restrict__ syno,
        uint32_t* __restrict__ synoHi, uint32_t* __restrict__ synoLo) {
    const int i = blockIdx.x * 256 + threadIdx.x;   // 0..8191
    const float x = syno[2 * i], y = syno[2 * i + 1];
    uint32_t h, lo;
    split2(x, y, &h, &lo);
    synoHi[i] = h;
    synoLo[i] = lo;
}

// ---------------------------------------------------------------------------
// Kernel 1 (v5): compensated bf16 MFMA Grams + fused spatial logits, with the
// conv accumulated in TWO passes (pass0 = q channels, pass1 = k channels) so
// the prob buffer is [16 slot][260 pix] fp32 = 16.6 KB -> ~7 blocks/CU.
// Conv weights come straight from tw via wave-uniform s_loads (no LDS).
// [slot][pix] layout: prob writes ~4-way worst case, conv reads stride-1
// conflict-free with uniform tap offsets. 3 barriers total.
// ---------------------------------------------------------------------------
__global__ __launch_bounds__(256) void k1_temporal(
        const float* __restrict__ qin, const float* __restrict__ kin,
        const float* __restrict__ tw,  const float* __restrict__ tbv,
        const uint32_t* __restrict__ synoHi, const uint32_t* __restrict__ synoLo,
        float* __restrict__ affRaw, float* __restrict__ SLout) {
    __shared__ __align__(16) float lds_c[16 * 260];   // [slot][pix]
    __shared__ __align__(16) float sl_part[4][16][16];

    const int bid = blockIdx.x, b = bid / LL, l = bid % LL;
    const int tid = threadIdx.x, wid = tid >> 6, lane = tid & 63;
    const int mrow = lane & 15;            // A-fragment row = frame
    const int g = lane >> 4;               // k-chunk group
    const int colb = lane & 15;
    const int oq = tid >> 4, ok = tid & 15;

    const size_t rowbase = ((size_t)(b*TT + mrow)*LP1 + 1 + l)*DM + g*8;
    f32x4 acc_sl = {0.f, 0.f, 0.f, 0.f};
    float accv = tbv[0];

    #pragma unroll
    for (int pass = 0; pass < 2; ++pass) {
        #pragma unroll
        for (int jj = 0; jj < 2; ++jj) {
            const int j = pass * 2 + jj;
            #pragma unroll
            for (int hf = 0; hf < 2; ++hf) {
                const int ch = 2*wid + 8*j + hf;        // channel 0..31
                const float* sp2 = (pass == 0) ? qin : kin;
                const float* base = sp2 + rowbase + (size_t)(ch & 15)*DD;
                const float4 a0 = *reinterpret_cast<const float4*>(base);
                const float4 a1 = *reinterpret_cast<const float4*>(base + 4);
                const float4 a2 = *reinterpret_cast<const float4*>(base + 32);
                const float4 a3 = *reinterpret_cast<const float4*>(base + 36);
                bf16x8 h1, l1, h2, l2;
                pksplit(a0, a1, h1, l1);
                pksplit(a2, a3, h2, l2);
                f32x4 acc = {0.f, 0.f, 0.f, 0.f};
                acc = __builtin_amdgcn_mfma_f32_16x16x32_bf16(h1, h1, acc, 0, 0, 0);
                acc = __builtin_amdgcn_mfma_f32_16x16x32_bf16(h1, l1, acc, 0, 0, 0);
                acc = __builtin_amdgcn_mfma_f32_16x16x32_bf16(l1, h1, acc, 0, 0, 0);
                acc = __builtin_amdgcn_mfma_f32_16x16x32_bf16(h2, h2, acc, 0, 0, 0);
                acc = __builtin_amdgcn_mfma_f32_16x16x32_bf16(h2, l2, acc, 0, 0, 0);
                acc = __builtin_amdgcn_mfma_f32_16x16x32_bf16(l2, h2, acc, 0, 0, 0);
                // fused spatial logits on k channels (pass 1)
                if (pass == 1) {
                    const int off = colb * 512 + (ch - 16) * 32 + g * 4;
                    const bf16x8 sh1 = *reinterpret_cast<const bf16x8*>(synoHi + off);
                    const bf16x8 sl1 = *reinterpret_cast<const bf16x8*>(synoLo + off);
                    const bf16x8 sh2 = *reinterpret_cast<const bf16x8*>(synoHi + off + 16);
                    const bf16x8 sl2 = *reinterpret_cast<const bf16x8*>(synoLo + off + 16);
                    acc_sl = __builtin_amdgcn_mfma_f32_16x16x32_bf16(h1, sh1, acc_sl, 0, 0, 0);
                    acc_sl = __builtin_amdgcn_mfma_f32_16x16x32_bf16(h1, sl1, acc_sl, 0, 0, 0);
                    acc_sl = __builtin_amdgcn_mfma_f32_16x16x32_bf16(l1, sh1, acc_sl, 0, 0, 0);
                    acc_sl = __builtin_amdgcn_mfma_f32_16x16x32_bf16(h2, sh2, acc_sl, 0, 0, 0);
                    acc_sl = __builtin_amdgcn_mfma_f32_16x16x32_bf16(h2, sl2, acc_sl, 0, 0, 0);
                    acc_sl = __builtin_amdgcn_mfma_f32_16x16x32_bf16(l2, sh2, acc_sl, 0, 0, 0);
                }
                // softmax over cols (keys); lane holds S[row=g*4+r][col=colb]
                const float x0 = acc[0]*0.125f, x1 = acc[1]*0.125f;
                const float x2 = acc[2]*0.125f, x3 = acc[3]*0.125f;
                float m0 = x0, m1 = x1, m2 = x2, m3 = x3;
                #pragma unroll
                for (int msk = 1; msk < 16; msk <<= 1) {
                    m0 = fmaxf(m0, __shfl_xor(m0, msk, 64));
                    m1 = fmaxf(m1, __shfl_xor(m1, msk, 64));
                    m2 = fmaxf(m2, __shfl_xor(m2, msk, 64));
                    m3 = fmaxf(m3, __shfl_xor(m3, msk, 64));
                }
                const float e0 = __expf(x0 - m0), e1 = __expf(x1 - m1);
                const float e2 = __expf(x2 - m2), e3 = __expf(x3 - m3);
                float s0 = e0, s1 = e1, s2 = e2, s3 = e3;
                #pragma unroll
                for (int msk = 1; msk < 16; msk <<= 1) {
                    s0 += __shfl_xor(s0, msk, 64);
                    s1 += __shfl_xor(s1, msk, 64);
                    s2 += __shfl_xor(s2, msk, 64);
                    s3 += __shfl_xor(s3, msk, 64);
                }
                const int slot = 2*wid + 8*jj + hf;     // 0..15 within pass
                float* cp = lds_c + slot * 260;
                cp[(g*4 + 0)*16 + colb] = e0 / s0;
                cp[(g*4 + 1)*16 + colb] = e1 / s1;
                cp[(g*4 + 2)*16 + colb] = e2 / s2;
                cp[(g*4 + 3)*16 + colb] = e3 / s3;
            }
        }
        if (pass == 1) {
            #pragma unroll
            for (int r = 0; r < 4; ++r)
                sl_part[wid][g * 4 + r][colb] = acc_sl[r];
        }
        __syncthreads();
        // conv partial over this pass's 16 channels (weights via s_load)
        #pragma unroll
        for (int ky = 0; ky < 3; ++ky) {
            const int iq = oq + ky - 1;
            if (iq < 0 || iq > 15) continue;
            #pragma unroll
            for (int kx = 0; kx < 3; ++kx) {
                const int ik = ok + kx - 1;
                if (ik < 0 || ik > 15) continue;
                const int pix = iq * 16 + ik;
                #pragma unroll
                for (int s = 0; s < 16; ++s)
                    accv += lds_c[s * 260 + pix] * tw[(pass*16 + s)*9 + ky*3 + kx];
            }
        }
        if (pass == 0) __syncthreads();   // before pass 1 overwrites lds_c
    }
    affRaw[(size_t)bid * T2 + tid] = accv;

    // SL reduce over the 4 waves + scaled write: thread = (t, q)
    {
        const int t = tid >> 4, qq = tid & 15;
        const float s = sl_part[0][t][qq] + sl_part[1][t][qq] +
                        sl_part[2][t][qq] + sl_part[3][t][qq];
        SLout[((size_t)(b * TT + t) * NS + qq) * LL + l] = s * 0.03125f;
    }
}

// ---------------------------------------------------------------------------
// Kernel 2: LayerNorm + MLP (gelu exact) + residual. 4 rows per block.
// ---------------------------------------------------------------------------
__global__ __launch_bounds__(256) void k2_mlp(
        const float* __restrict__ affRaw,
        const float* __restrict__ lng, const float* __restrict__ lnb,
        const float* __restrict__ w1, const float* __restrict__ b1,
        const float* __restrict__ w2, const float* __restrict__ b2,
        float* __restrict__ affRes) {
    __shared__ __align__(16) float lx[4 * 256];
    __shared__ __align__(16) float lln[4 * 256];
    __shared__ __align__(16) float lg[4 * 256];
    const int tid = threadIdx.x;
    const int wave = tid >> 6, lane = tid & 63;
    const int i0 = blockIdx.x * 4;
    {
        const float* xr = affRaw + (size_t)(i0 + wave) * 256;
        float4 x = reinterpret_cast<const float4*>(xr)[lane];
        float sm = x.x + x.y + x.z + x.w;
        float ss = x.x * x.x + x.y * x.y + x.z * x.z + x.w * x.w;
        #pragma unroll
        for (int m = 1; m < 64; m <<= 1) {
            sm += __shfl_xor(sm, m, 64);
            ss += __shfl_xor(ss, m, 64);
        }
        const float mean = sm * (1.f / 256.f);
        const float var = ss * (1.f / 256.f) - mean * mean;
        const float inv = rsqrtf(var + 1e-5f);
        const float4 g4 = reinterpret_cast<const float4*>(lng)[lane];
        const float4 bb = reinterpret_cast<const float4*>(lnb)[lane];
        float4 ln;
        ln.x = (x.x - mean) * inv * g4.x + bb.x;
        ln.y = (x.y - mean) * inv * g4.y + bb.y;
        ln.z = (x.z - mean) * inv * g4.z + bb.z;
        ln.w = (x.w - mean) * inv * g4.w + bb.w;
        reinterpret_cast<float4*>(lx + wave * 256)[lane] = x;
        reinterpret_cast<float4*>(lln + wave * 256)[lane] = ln;
    }
    __syncthreads();
    const int j = tid;
    float a0 = 0.f, a1 = 0.f, a2 = 0.f, a3 = 0.f;
    {
        const float4* wr = reinterpret_cast<const float4*>(w1 + (size_t)j * 256);
        const float4* l0 = reinterpret_cast<const float4*>(lln);
        const float4* l1 = reinterpret_cast<const float4*>(lln + 256);
        const float4* l2 = reinterpret_cast<const float4*>(lln + 512);
        const float4* l3 = reinterpret_cast<const float4*>(lln + 768);
        #pragma unroll 8
        for (int m4 = 0; m4 < 64; ++m4) {
            const float4 w = wr[m4];
            a0 += dot4(w, l0[m4]); a1 += dot4(w, l1[m4]);
            a2 += dot4(w, l2[m4]); a3 += dot4(w, l3[m4]);
        }
    }
    const float bj = b1[j];
    const float kInvSqrt2 = 0.70710678118654752f;
    float h0 = a0 + bj, h1 = a1 + bj, h2 = a2 + bj, h3 = a3 + bj;
    lg[0 * 256 + j] = 0.5f * h0 * (1.f + erff(h0 * kInvSqrt2));
    lg[1 * 256 + j] = 0.5f * h1 * (1.f + erff(h1 * kInvSqrt2));
    lg[2 * 256 + j] = 0.5f * h2 * (1.f + erff(h2 * kInvSqrt2));
    lg[3 * 256 + j] = 0.5f * h3 * (1.f + erff(h3 * kInvSqrt2));
    __syncthreads();
    a0 = a1 = a2 = a3 = 0.f;
    {
        const float4* wr = reinterpret_cast<const float4*>(w2 + (size_t)j * 256);
        const float4* l0 = reinterpret_cast<const float4*>(lg);
        const float4* l1 = reinterpret_cast<const float4*>(lg + 256);
        const float4* l2 = reinterpret_cast<const float4*>(lg + 512);
        const float4* l3 = reinterpret_cast<const float4*>(lg + 768);
        #pragma unroll 8
        for (int m4 = 0; m4 < 64; ++m4) {
            const float4 w = wr[m4];
            a0 += dot4(w, l0[m4]); a1 += dot4(w, l1[m4]);
            a2 += dot4(w, l2[m4]); a3 += dot4(w, l3[m4]);
        }
    }
    const float b2j = b2[j];
    affRes[(size_t)(i0 + 0) * 256 + j] = lx[0 * 256 + j] + a0 + b2j;
    affRes[(size_t)(i0 + 1) * 256 + j] = lx[1 * 256 + j] + a1 + b2j;
    affRes[(size_t)(i0 + 2) * 256 + j] = lx[2 * 256 + j] + a2 + b2j;
    affRes[(size_t)(i0 + 3) * 256 + j] = lx[3 * 256 + j] + a3 + b2j;
}

// ---------------------------------------------------------------------------
// Kernel 3a: patch-grid 3x3 conv over 256 channels, split 64-ch per block.
// ---------------------------------------------------------------------------
__global__ __launch_bounds__(256) void k3a_pconv(
        const float* __restrict__ affRes, const float* __restrict__ pw,
        float* __restrict__ part) {
    __shared__ __align__(16) float lpw[576];
    const int b = blockIdx.x >> 2, cc = blockIdx.x & 3;
    const int tid = threadIdx.x;
    for (int idx = tid; idx < 576; idx += 256) {
        const int kk = idx / 64, c = idx & 63;
        lpw[kk * 64 + c] = pw[(size_t)(cc * 64 + c) * 9 + kk];
    }
    __syncthreads();
    if (tid < 196) {
        const int p1 = tid / 14, p2 = tid % 14;
        float s = 0.f;
        #pragma unroll
        for (int ky = 0; ky < 3; ++ky) {
            const int ip1 = p1 + ky - 1;
            if (ip1 < 0 || ip1 > 13) continue;
            #pragma unroll
            for (int kx = 0; kx < 3; ++kx) {
                const int ip2 = p2 + kx - 1;
                if (ip2 < 0 || ip2 > 13) continue;
                const float4* ar = reinterpret_cast<const float4*>(
                    affRes + (size_t)(b * LL + ip1 * 14 + ip2) * 256 + cc * 64);
                const float4* wr = reinterpret_cast<const float4*>(lpw + (ky * 3 + kx) * 64);
                #pragma unroll
                for (int c4 = 0; c4 < 16; ++c4) s += dot4(ar[c4], wr[c4]);
            }
        }
        part[(cc * 8 + b) * 196 + tid] = s;
    }
}

__global__ void k3b_yt(const float* __restrict__ part,
                       const float* __restrict__ pcb, float* __restrict__ out) {
    const int b = blockIdx.x, tid = threadIdx.x;
    if (tid < 196) {
        float s = pcb[0];
        #pragma unroll
        for (int cc = 0; cc < 4; ++cc) s += part[(cc * 8 + b) * 196 + tid];
        out[b * 196 + tid] = s;
    }
}

// Kernel 4b: softmax over l per (b,t,q) + sum over q -> WSUM[b,t,l]
__global__ __launch_bounds__(256) void k4b_softmax(
        const float* __restrict__ SL, float* __restrict__ WSUM) {
    __shared__ float lp[16 * 200];
    const int t = blockIdx.x, b = blockIdx.y;
    const int tid = threadIdx.x;
    const int qq = tid >> 4, j = tid & 15;
    const float* row = SL + (size_t)((b * TT + t) * NS + qq) * LL;
    float v[13];
    float m = -1e30f;
    #pragma unroll
    for (int i = 0; i < 13; ++i) {
        const int l = j + i * 16;
        v[i] = (l < LL) ? row[l] : -1e30f;
        m = fmaxf(m, v[i]);
    }
    #pragma unroll
    for (int msk = 1; msk < 16; msk <<= 1) m = fmaxf(m, __shfl_xor(m, msk, 64));
    float s = 0.f;
    #pragma unroll
    for (int i = 0; i < 13; ++i) {
        const int l = j + i * 16;
        v[i] = (l < LL) ? __expf(v[i] - m) : 0.f;
        s += v[i];
    }
    #pragma unroll
    for (int msk = 1; msk < 16; msk <<= 1) s += __shfl_xor(s, msk, 64);
    const float inv = 1.f / s;
    #pragma unroll
    for (int i = 0; i < 13; ++i) {
        const int l = j + i * 16;
        if (l < LL) lp[qq * 200 + l] = v[i] * inv;
    }
    __syncthreads();
    if (tid < LL) {
        float w = 0.f;
        #pragma unroll
        for (int qi = 0; qi < 16; ++qi) w += lp[qi * 200 + tid];
        WSUM[(size_t)(b * TT + t) * LL + tid] = w;
    }
}

// Kernel 4c: PS[bt][z][:] = sum over 98 rows of WSUM * v  (z-split over l)
__global__ __launch_bounds__(256) void k4c_vsum(
        const float* __restrict__ vin, const float* __restrict__ WSUM,
        float* __restrict__ PS) {
    __shared__ float lw[98];
    const int t = blockIdx.x, b = blockIdx.y, z = blockIdx.z;
    const int tid = threadIdx.x;
    const int bt = b * TT + t;
    if (tid < 98) lw[tid] = WSUM[(size_t)bt * LL + z * 98 + tid];
    __syncthreads();
    float4 acc = make_float4(0.f, 0.f, 0.f, 0.f);
    const float* vb = vin + ((size_t)bt * LP1 + 1 + z * 98) * DM + tid * 4;
    #pragma unroll 4
    for (int l = 0; l < 98; ++l) {
        const float4 v = *reinterpret_cast<const float4*>(vb + (size_t)l * DM);
        const float w = lw[l];
        acc.x += w * v.x; acc.y += w * v.y; acc.z += w * v.z; acc.w += w * v.w;
    }
    *reinterpret_cast<float4*>(PS + ((size_t)bt * 2 + z) * DM + tid * 4) = acc;
}

// Kernel 4d: y_s[b,w] = (1/256) * sum over 32 (t,z) partials
__global__ void k4d_ys(const float* __restrict__ PS, float* __restrict__ out) {
    const int i = blockIdx.x * 256 + threadIdx.x;   // 0..8191
    const int b = i >> 10, w = i & 1023;
    float s = 0.f;
    #pragma unroll
    for (int tz = 0; tz < 32; ++tz) s += PS[((size_t)b * 32 + tz) * DM + w];
    out[1568 + i] = s * (1.f / 256.f);
}

// ---------------------------------------------------------------------------
extern "C" void kernel_launch(void* const* d_in, const int* in_sizes, int n_in,
                              void* d_out, int out_size, void* d_ws, size_t ws_size,
                              hipStream_t stream) {
    const float* q    = (const float*)d_in[0];
    const float* k    = (const float*)d_in[1];
    const float* v    = (const float*)d_in[2];
    const float* syno = (const float*)d_in[3];
    const float* tw   = (const float*)d_in[4];
    const float* tbv  = (const float*)d_in[5];
    const float* lng  = (const float*)d_in[6];
    const float* lnb  = (const float*)d_in[7];
    const float* w1   = (const float*)d_in[8];
    const float* b1   = (const float*)d_in[9];
    const float* w2   = (const float*)d_in[10];
    const float* b2   = (const float*)d_in[11];
    const float* pw   = (const float*)d_in[12];
    const float* pcb  = (const float*)d_in[13];
    float* out = (float*)d_out;

    float* ws = (float*)d_ws;
    float* affRaw = ws;                 // 401408 floats (dead after k2)
    float* affRes = ws + 401408;        // 401408
    float* SL     = ws + 802816;        // 401408
    float* WSUM   = ws + 1204224;       // 25088
    float* part   = ws + 1229312;       // 6272
    uint32_t* synoHi = (uint32_t*)(ws + 1235584);   // 8192 u32
    uint32_t* synoLo = (uint32_t*)(ws + 1243776);   // 8192 u32
    float* PS     = ws;                 // 262144, aliases affRaw (k4c after k2)

    // syno pre-split (hi/lo bf16)
    hipLaunchKernelGGL(kprep, dim3(32), dim3(256), 0, stream, syno, synoHi, synoLo);
    // temporal path + fused spatial logits
    hipLaunchKernelGGL(k1_temporal, dim3(BB * LL), dim3(256), 0, stream,
                       q, k, tw, tbv, synoHi, synoLo, affRaw, SL);
    hipLaunchKernelGGL(k2_mlp, dim3(392), dim3(256), 0, stream,
                       affRaw, lng, lnb, w1, b1, w2, b2, affRes);
    hipLaunchKernelGGL(k3a_pconv, dim3(32), dim3(256), 0, stream,
                       affRes, pw, part);
    hipLaunchKernelGGL(k3b_yt, dim3(8), dim3(256), 0, stream, part, pcb, out);
    // spatial path (k4a fused into k1)
    hipLaunchKernelGGL(k4b_softmax, dim3(16, 8), dim3(256), 0, stream, SL, WSUM);
    hipLaunchKernelGGL(k4c_vsum, dim3(16, 8, 2), dim3(256), 0, stream, v, WSUM, PS);
    hipLaunchKernelGGL(k4d_ys, dim3(32), dim3(256), 0, stream, PS, out);
}

// Round 10
// 145.995 us; speedup vs baseline: 3.3785x; 1.0226x over previous
//
#include <hip/hip_runtime.h>
#include <hip/hip_bf16.h>
#include <math.h>

// Problem constants
#define BB 8
#define TT 16
#define PP 14
#define LL 196      // P*P
#define HH 16
#define DD 64
#define DM 1024     // H*D
#define NS 16
#define T2 256      // T*T
#define LP1 197

using bf16x8 = __attribute__((ext_vector_type(8))) short;
using f32x4  = __attribute__((ext_vector_type(4))) float;

__device__ __forceinline__ float dot4(float4 a, float4 b) {
    return a.x*b.x + a.y*b.y + a.z*b.z + a.w*b.w;
}

// round-to-nearest-even bf16 pack of two finite fp32
__device__ __forceinline__ uint32_t pkbf(float lo, float hi) {
    uint32_t a = __builtin_bit_cast(uint32_t, lo);
    uint32_t b = __builtin_bit_cast(uint32_t, hi);
    a += 0x7FFFu + ((a >> 16) & 1u);
    b += 0x7FFFu + ((b >> 16) & 1u);
    return (a >> 16) | (b & 0xFFFF0000u);
}

// split pair (x,y) into hi/lo bf16 words: x ~= hi.x + lo.x exactly to ~2^-18
__device__ __forceinline__ void split2(float x, float y, uint32_t* h, uint32_t* lo) {
    const uint32_t hh = pkbf(x, y);
    const float hx = __builtin_bit_cast(float, hh << 16);
    const float hy = __builtin_bit_cast(float, hh & 0xFFFF0000u);
    *h = hh;
    *lo = pkbf(x - hx, y - hy);
}

__device__ __forceinline__ void pksplit(float4 p, float4 q, bf16x8& hi, bf16x8& lo) {
    uint32_t uh[4], ul[4];
    split2(p.x, p.y, &uh[0], &ul[0]);
    split2(p.z, p.w, &uh[1], &ul[1]);
    split2(q.x, q.y, &uh[2], &ul[2]);
    split2(q.z, q.w, &uh[3], &ul[3]);
    struct U4 { uint32_t v[4]; } th, tl;
    th.v[0] = uh[0]; th.v[1] = uh[1]; th.v[2] = uh[2]; th.v[3] = uh[3];
    tl.v[0] = ul[0]; tl.v[1] = ul[1]; tl.v[2] = ul[2]; tl.v[3] = ul[3];
    hi = __builtin_bit_cast(bf16x8, th);
    lo = __builtin_bit_cast(bf16x8, tl);
}

// ---------------------------------------------------------------------------
// Kernel 0: pre-split syno (16x1024 fp32) into hi/lo bf16 pair-words.
// ---------------------------------------------------------------------------
__global__ __launch_bounds__(256) void kprep(
        const float* __restrict__ syno,
        uint32_t* __restrict__ synoHi, uint32_t* __restrict__ synoLo) {
    const int i = blockIdx.x * 256 + threadIdx.x;   // 0..8191
    const float x = syno[2 * i], y = syno[2 * i + 1];
    uint32_t h, lo;
    split2(x, y, &h, &lo);
    synoHi[i] = h;
    synoLo[i] = lo;
}

// ---------------------------------------------------------------------------
// Kernel 1 (v6): v5 + explicit depth-2 register pipelining of the 8 channel
// iterations (prefetch iter i+1's global loads before computing iter i).
// All buffer indices are compile-time after unroll (no scratch spill).
// Two conv passes as in v5; LDS ~20.6 KB.
// ---------------------------------------------------------------------------
__global__ __launch_bounds__(256) void k1_temporal(
        const float* __restrict__ qin, const float* __restrict__ kin,
        const float* __restrict__ tw,  const float* __restrict__ tbv,
        const uint32_t* __restrict__ synoHi, const uint32_t* __restrict__ synoLo,
        float* __restrict__ affRaw, float* __restrict__ SLout) {
    __shared__ __align__(16) float lds_c[16 * 260];   // [slot][pix]
    __shared__ __align__(16) float sl_part[4][16][16];

    const int bid = blockIdx.x, b = bid / LL, l = bid % LL;
    const int tid = threadIdx.x, wid = tid >> 6, lane = tid & 63;
    const int mrow = lane & 15;            // A-fragment row = frame
    const int g = lane >> 4;               // k-chunk group
    const int colb = lane & 15;
    const int oq = tid >> 4, ok = tid & 15;

    const size_t rowbase = ((size_t)(b*TT + mrow)*LP1 + 1 + l)*DM + g*8;
    f32x4 acc_sl = {0.f, 0.f, 0.f, 0.f};
    float accv = tbv[0];

    float4 A[2][4];
    uint4  S[2][4];

    // iteration mapping: it = pass*4 + jj*2 + hf; ch = 2*wid + 8*(it>>1) + (it&1)
#define K1_LOAD(BUF, IT) do {                                                  \
        const int ch_ = 2*wid + 8*((IT) >> 1) + ((IT) & 1);                    \
        const float* sp_ = ((IT) < 4) ? qin : kin;                             \
        const float* base_ = sp_ + rowbase + (size_t)(ch_ & 15) * DD;          \
        A[BUF][0] = *reinterpret_cast<const float4*>(base_);                   \
        A[BUF][1] = *reinterpret_cast<const float4*>(base_ + 4);               \
        A[BUF][2] = *reinterpret_cast<const float4*>(base_ + 32);              \
        A[BUF][3] = *reinterpret_cast<const float4*>(base_ + 36);              \
        if ((IT) >= 4) {                                                       \
            const int off_ = colb * 512 + (ch_ - 16) * 32 + g * 4;             \
            S[BUF][0] = *reinterpret_cast<const uint4*>(synoHi + off_);        \
            S[BUF][1] = *reinterpret_cast<const uint4*>(synoLo + off_);        \
            S[BUF][2] = *reinterpret_cast<const uint4*>(synoHi + off_ + 16);   \
            S[BUF][3] = *reinterpret_cast<const uint4*>(synoLo + off_ + 16);   \
        }                                                                      \
    } while (0)

#define K1_COMP(BUF, IT) do {                                                  \
        bf16x8 h1, l1, h2, l2;                                                 \
        pksplit(A[BUF][0], A[BUF][1], h1, l1);                                 \
        pksplit(A[BUF][2], A[BUF][3], h2, l2);                                 \
        f32x4 acc = {0.f, 0.f, 0.f, 0.f};                                      \
        acc = __builtin_amdgcn_mfma_f32_16x16x32_bf16(h1, h1, acc, 0, 0, 0);   \
        acc = __builtin_amdgcn_mfma_f32_16x16x32_bf16(h1, l1, acc, 0, 0, 0);   \
        acc = __builtin_amdgcn_mfma_f32_16x16x32_bf16(l1, h1, acc, 0, 0, 0);   \
        acc = __builtin_amdgcn_mfma_f32_16x16x32_bf16(h2, h2, acc, 0, 0, 0);   \
        acc = __builtin_amdgcn_mfma_f32_16x16x32_bf16(h2, l2, acc, 0, 0, 0);   \
        acc = __builtin_amdgcn_mfma_f32_16x16x32_bf16(l2, h2, acc, 0, 0, 0);   \
        if ((IT) >= 4) {                                                       \
            const bf16x8 sh1 = __builtin_bit_cast(bf16x8, S[BUF][0]);          \
            const bf16x8 sl1 = __builtin_bit_cast(bf16x8, S[BUF][1]);          \
            const bf16x8 sh2 = __builtin_bit_cast(bf16x8, S[BUF][2]);          \
            const bf16x8 sl2 = __builtin_bit_cast(bf16x8, S[BUF][3]);          \
            acc_sl = __builtin_amdgcn_mfma_f32_16x16x32_bf16(h1, sh1, acc_sl, 0, 0, 0); \
            acc_sl = __builtin_amdgcn_mfma_f32_16x16x32_bf16(h1, sl1, acc_sl, 0, 0, 0); \
            acc_sl = __builtin_amdgcn_mfma_f32_16x16x32_bf16(l1, sh1, acc_sl, 0, 0, 0); \
            acc_sl = __builtin_amdgcn_mfma_f32_16x16x32_bf16(h2, sh2, acc_sl, 0, 0, 0); \
            acc_sl = __builtin_amdgcn_mfma_f32_16x16x32_bf16(h2, sl2, acc_sl, 0, 0, 0); \
            acc_sl = __builtin_amdgcn_mfma_f32_16x16x32_bf16(l2, sh2, acc_sl, 0, 0, 0); \
        }                                                                      \
        const float x0 = acc[0]*0.125f, x1 = acc[1]*0.125f;                    \
        const float x2 = acc[2]*0.125f, x3 = acc[3]*0.125f;                    \
        float m0 = x0, m1 = x1, m2 = x2, m3 = x3;                              \
        _Pragma("unroll")                                                      \
        for (int msk = 1; msk < 16; msk <<= 1) {                               \
            m0 = fmaxf(m0, __shfl_xor(m0, msk, 64));                           \
            m1 = fmaxf(m1, __shfl_xor(m1, msk, 64));                           \
            m2 = fmaxf(m2, __shfl_xor(m2, msk, 64));                           \
            m3 = fmaxf(m3, __shfl_xor(m3, msk, 64));                           \
        }                                                                      \
        const float e0 = __expf(x0 - m0), e1 = __expf(x1 - m1);                \
        const float e2 = __expf(x2 - m2), e3 = __expf(x3 - m3);                \
        float s0 = e0, s1 = e1, s2 = e2, s3 = e3;                              \
        _Pragma("unroll")                                                      \
        for (int msk = 1; msk < 16; msk <<= 1) {                               \
            s0 += __shfl_xor(s0, msk, 64);                                     \
            s1 += __shfl_xor(s1, msk, 64);                                     \
            s2 += __shfl_xor(s2, msk, 64);                                     \
            s3 += __shfl_xor(s3, msk, 64);                                     \
        }                                                                      \
        const int slot_ = 2*wid + 8*(((IT) >> 1) & 1) + ((IT) & 1);            \
        float* cp_ = lds_c + slot_ * 260;                                      \
        cp_[(g*4 + 0)*16 + colb] = e0 / s0;                                    \
        cp_[(g*4 + 1)*16 + colb] = e1 / s1;                                    \
        cp_[(g*4 + 2)*16 + colb] = e2 / s2;                                    \
        cp_[(g*4 + 3)*16 + colb] = e3 / s3;                                    \
    } while (0)

#define K1_CONV(PASS) do {                                                     \
        _Pragma("unroll")                                                      \
        for (int ky = 0; ky < 3; ++ky) {                                       \
            const int iq = oq + ky - 1;                                        \
            if (iq < 0 || iq > 15) continue;                                   \
            _Pragma("unroll")                                                  \
            for (int kx = 0; kx < 3; ++kx) {                                   \
                const int ik = ok + kx - 1;                                    \
                if (ik < 0 || ik > 15) continue;                               \
                const int pix = iq * 16 + ik;                                  \
                _Pragma("unroll")                                              \
                for (int s = 0; s < 16; ++s)                                   \
                    accv += lds_c[s * 260 + pix] * tw[((PASS)*16 + s)*9 + ky*3 + kx]; \
            }                                                                  \
        }                                                                      \
    } while (0)

    K1_LOAD(0, 0);
    #pragma unroll
    for (int it = 0; it < 8; ++it) {
        if (it < 7) {
            switch (it & 1) {     // compile-time after unroll
                case 0: K1_LOAD(1, it + 1); break;
                default: K1_LOAD(0, it + 1); break;
            }
        }
        switch (it & 1) {
            case 0: K1_COMP(0, it); break;
            default: K1_COMP(1, it); break;
        }
        if (it == 3) {
            __syncthreads();
            K1_CONV(0);
            __syncthreads();
        }
    }

    // per-wave SL partials
    #pragma unroll
    for (int r = 0; r < 4; ++r)
        sl_part[wid][g * 4 + r][colb] = acc_sl[r];
    __syncthreads();
    K1_CONV(1);

    affRaw[(size_t)bid * T2 + tid] = accv;

    // SL reduce over the 4 waves + scaled write: thread = (t, q)
    {
        const int t = tid >> 4, qq = tid & 15;
        const float s = sl_part[0][t][qq] + sl_part[1][t][qq] +
                        sl_part[2][t][qq] + sl_part[3][t][qq];
        SLout[((size_t)(b * TT + t) * NS + qq) * LL + l] = s * 0.03125f;
    }
#undef K1_LOAD
#undef K1_COMP
#undef K1_CONV
}

// ---------------------------------------------------------------------------
// Kernel 2: LayerNorm + MLP (gelu exact) + residual. 4 rows per block.
// ---------------------------------------------------------------------------
__global__ __launch_bounds__(256) void k2_mlp(
        const float* __restrict__ affRaw,
        const float* __restrict__ lng, const float* __restrict__ lnb,
        const float* __restrict__ w1, const float* __restrict__ b1,
        const float* __restrict__ w2, const float* __restrict__ b2,
        float* __restrict__ affRes) {
    __shared__ __align__(16) float lx[4 * 256];
    __shared__ __align__(16) float lln[4 * 256];
    __shared__ __align__(16) float lg[4 * 256];
    const int tid = threadIdx.x;
    const int wave = tid >> 6, lane = tid & 63;
    const int i0 = blockIdx.x * 4;
    {
        const float* xr = affRaw + (size_t)(i0 + wave) * 256;
        float4 x = reinterpret_cast<const float4*>(xr)[lane];
        float sm = x.x + x.y + x.z + x.w;
        float ss = x.x * x.x + x.y * x.y + x.z * x.z + x.w * x.w;
        #pragma unroll
        for (int m = 1; m < 64; m <<= 1) {
            sm += __shfl_xor(sm, m, 64);
            ss += __shfl_xor(ss, m, 64);
        }
        const float mean = sm * (1.f / 256.f);
        const float var = ss * (1.f / 256.f) - mean * mean;
        const float inv = rsqrtf(var + 1e-5f);
        const float4 g4 = reinterpret_cast<const float4*>(lng)[lane];
        const float4 bb = reinterpret_cast<const float4*>(lnb)[lane];
        float4 ln;
        ln.x = (x.x - mean) * inv * g4.x + bb.x;
        ln.y = (x.y - mean) * inv * g4.y + bb.y;
        ln.z = (x.z - mean) * inv * g4.z + bb.z;
        ln.w = (x.w - mean) * inv * g4.w + bb.w;
        reinterpret_cast<float4*>(lx + wave * 256)[lane] = x;
        reinterpret_cast<float4*>(lln + wave * 256)[lane] = ln;
    }
    __syncthreads();
    const int j = tid;
    float a0 = 0.f, a1 = 0.f, a2 = 0.f, a3 = 0.f;
    {
        const float4* wr = reinterpret_cast<const float4*>(w1 + (size_t)j * 256);
        const float4* l0 = reinterpret_cast<const float4*>(lln);
        const float4* l1 = reinterpret_cast<const float4*>(lln + 256);
        const float4* l2 = reinterpret_cast<const float4*>(lln + 512);
        const float4* l3 = reinterpret_cast<const float4*>(lln + 768);
        #pragma unroll 8
        for (int m4 = 0; m4 < 64; ++m4) {
            const float4 w = wr[m4];
            a0 += dot4(w, l0[m4]); a1 += dot4(w, l1[m4]);
            a2 += dot4(w, l2[m4]); a3 += dot4(w, l3[m4]);
        }
    }
    const float bj = b1[j];
    const float kInvSqrt2 = 0.70710678118654752f;
    float h0 = a0 + bj, h1 = a1 + bj, h2 = a2 + bj, h3 = a3 + bj;
    lg[0 * 256 + j] = 0.5f * h0 * (1.f + erff(h0 * kInvSqrt2));
    lg[1 * 256 + j] = 0.5f * h1 * (1.f + erff(h1 * kInvSqrt2));
    lg[2 * 256 + j] = 0.5f * h2 * (1.f + erff(h2 * kInvSqrt2));
    lg[3 * 256 + j] = 0.5f * h3 * (1.f + erff(h3 * kInvSqrt2));
    __syncthreads();
    a0 = a1 = a2 = a3 = 0.f;
    {
        const float4* wr = reinterpret_cast<const float4*>(w2 + (size_t)j * 256);
        const float4* l0 = reinterpret_cast<const float4*>(lg);
        const float4* l1 = reinterpret_cast<const float4*>(lg + 256);
        const float4* l2 = reinterpret_cast<const float4*>(lg + 512);
        const float4* l3 = reinterpret_cast<const float4*>(lg + 768);
        #pragma unroll 8
        for (int m4 = 0; m4 < 64; ++m4) {
            const float4 w = wr[m4];
            a0 += dot4(w, l0[m4]); a1 += dot4(w, l1[m4]);
            a2 += dot4(w, l2[m4]); a3 += dot4(w, l3[m4]);
        }
    }
    const float b2j = b2[j];
    affRes[(size_t)(i0 + 0) * 256 + j] = lx[0 * 256 + j] + a0 + b2j;
    affRes[(size_t)(i0 + 1) * 256 + j] = lx[1 * 256 + j] + a1 + b2j;
    affRes[(size_t)(i0 + 2) * 256 + j] = lx[2 * 256 + j] + a2 + b2j;
    affRes[(size_t)(i0 + 3) * 256 + j] = lx[3 * 256 + j] + a3 + b2j;
}

// ---------------------------------------------------------------------------
// Kernel 3a: patch-grid 3x3 conv over 256 channels, split 64-ch per block.
// ---------------------------------------------------------------------------
__global__ __launch_bounds__(256) void k3a_pconv(
        const float* __restrict__ affRes, const float* __restrict__ pw,
        float* __restrict__ part) {
    __shared__ __align__(16) float lpw[576];
    const int b = blockIdx.x >> 2, cc = blockIdx.x & 3;
    const int tid = threadIdx.x;
    for (int idx = tid; idx < 576; idx += 256) {
        const int kk = idx / 64, c = idx & 63;
        lpw[kk * 64 + c] = pw[(size_t)(cc * 64 + c) * 9 + kk];
    }
    __syncthreads();
    if (tid < 196) {
        const int p1 = tid / 14, p2 = tid % 14;
        float s = 0.f;
        #pragma unroll
        for (int ky = 0; ky < 3; ++ky) {
            const int ip1 = p1 + ky - 1;
            if (ip1 < 0 || ip1 > 13) continue;
            #pragma unroll
            for (int kx = 0; kx < 3; ++kx) {
                const int ip2 = p2 + kx - 1;
                if (ip2 < 0 || ip2 > 13) continue;
                const float4* ar = reinterpret_cast<const float4*>(
                    affRes + (size_t)(b * LL + ip1 * 14 + ip2) * 256 + cc * 64);
                const float4* wr = reinterpret_cast<const float4*>(lpw + (ky * 3 + kx) * 64);
                #pragma unroll
                for (int c4 = 0; c4 < 16; ++c4) s += dot4(ar[c4], wr[c4]);
            }
        }
        part[(cc * 8 + b) * 196 + tid] = s;
    }
}

__global__ void k3b_yt(const float* __restrict__ part,
                       const float* __restrict__ pcb, float* __restrict__ out) {
    const int b = blockIdx.x, tid = threadIdx.x;
    if (tid < 196) {
        float s = pcb[0];
        #pragma unroll
        for (int cc = 0; cc < 4; ++cc) s += part[(cc * 8 + b) * 196 + tid];
        out[b * 196 + tid] = s;
    }
}

// Kernel 4b: softmax over l per (b,t,q) + sum over q -> WSUM[b,t,l]
__global__ __launch_bounds__(256) void k4b_softmax(
        const float* __restrict__ SL, float* __restrict__ WSUM) {
    __shared__ float lp[16 * 200];
    const int t = blockIdx.x, b = blockIdx.y;
    const int tid = threadIdx.x;
    const int qq = tid >> 4, j = tid & 15;
    const float* row = SL + (size_t)((b * TT + t) * NS + qq) * LL;
    float v[13];
    float m = -1e30f;
    #pragma unroll
    for (int i = 0; i < 13; ++i) {
        const int l = j + i * 16;
        v[i] = (l < LL) ? row[l] : -1e30f;
        m = fmaxf(m, v[i]);
    }
    #pragma unroll
    for (int msk = 1; msk < 16; msk <<= 1) m = fmaxf(m, __shfl_xor(m, msk, 64));
    float s = 0.f;
    #pragma unroll
    for (int i = 0; i < 13; ++i) {
        const int l = j + i * 16;
        v[i] = (l < LL) ? __expf(v[i] - m) : 0.f;
        s += v[i];
    }
    #pragma unroll
    for (int msk = 1; msk < 16; msk <<= 1) s += __shfl_xor(s, msk, 64);
    const float inv = 1.f / s;
    #pragma unroll
    for (int i = 0; i < 13; ++i) {
        const int l = j + i * 16;
        if (l < LL) lp[qq * 200 + l] = v[i] * inv;
    }
    __syncthreads();
    if (tid < LL) {
        float w = 0.f;
        #pragma unroll
        for (int qi = 0; qi < 16; ++qi) w += lp[qi * 200 + tid];
        WSUM[(size_t)(b * TT + t) * LL + tid] = w;
    }
}

// Kernel 4c: PS[bt][z][:] = sum over 98 rows of WSUM * v  (z-split over l)
__global__ __launch_bounds__(256) void k4c_vsum(
        const float* __restrict__ vin, const float* __restrict__ WSUM,
        float* __restrict__ PS) {
    __shared__ float lw[98];
    const int t = blockIdx.x, b = blockIdx.y, z = blockIdx.z;
    const int tid = threadIdx.x;
    const int bt = b * TT + t;
    if (tid < 98) lw[tid] = WSUM[(size_t)bt * LL + z * 98 + tid];
    __syncthreads();
    float4 acc = make_float4(0.f, 0.f, 0.f, 0.f);
    const float* vb = vin + ((size_t)bt * LP1 + 1 + z * 98) * DM + tid * 4;
    #pragma unroll 4
    for (int l = 0; l < 98; ++l) {
        const float4 v = *reinterpret_cast<const float4*>(vb + (size_t)l * DM);
        const float w = lw[l];
        acc.x += w * v.x; acc.y += w * v.y; acc.z += w * v.z; acc.w += w * v.w;
    }
    *reinterpret_cast<float4*>(PS + ((size_t)bt * 2 + z) * DM + tid * 4) = acc;
}

// Kernel 4d: y_s[b,w] = (1/256) * sum over 32 (t,z) partials
__global__ void k4d_ys(const float* __restrict__ PS, float* __restrict__ out) {
    const int i = blockIdx.x * 256 + threadIdx.x;   // 0..8191
    const int b = i >> 10, w = i & 1023;
    float s = 0.f;
    #pragma unroll
    for (int tz = 0; tz < 32; ++tz) s += PS[((size_t)b * 32 + tz) * DM + w];
    out[1568 + i] = s * (1.f / 256.f);
}

// ---------------------------------------------------------------------------
extern "C" void kernel_launch(void* const* d_in, const int* in_sizes, int n_in,
                              void* d_out, int out_size, void* d_ws, size_t ws_size,
                              hipStream_t stream) {
    const float* q    = (const float*)d_in[0];
    const float* k    = (const float*)d_in[1];
    const float* v    = (const float*)d_in[2];
    const float* syno = (const float*)d_in[3];
    const float* tw   = (const float*)d_in[4];
    const float* tbv  = (const float*)d_in[5];
    const float* lng  = (const float*)d_in[6];
    const float* lnb  = (const float*)d_in[7];
    const float* w1   = (const float*)d_in[8];
    const float* b1   = (const float*)d_in[9];
    const float* w2   = (const float*)d_in[10];
    const float* b2   = (const float*)d_in[11];
    const float* pw   = (const float*)d_in[12];
    const float* pcb  = (const float*)d_in[13];
    float* out = (float*)d_out;

    float* ws = (float*)d_ws;
    float* affRaw = ws;                 // 401408 floats (dead after k2)
    float* affRes = ws + 401408;        // 401408
    float* SL     = ws + 802816;        // 401408
    float* WSUM   = ws + 1204224;       // 25088
    float* part   = ws + 1229312;       // 6272
    uint32_t* synoHi = (uint32_t*)(ws + 1235584);   // 8192 u32
    uint32_t* synoLo = (uint32_t*)(ws + 1243776);   // 8192 u32
    float* PS     = ws;                 // 262144, aliases affRaw (k4c after k2)

    // syno pre-split (hi/lo bf16)
    hipLaunchKernelGGL(kprep, dim3(32), dim3(256), 0, stream, syno, synoHi, synoLo);
    // temporal path + fused spatial logits
    hipLaunchKernelGGL(k1_temporal, dim3(BB * LL), dim3(256), 0, stream,
                       q, k, tw, tbv, synoHi, synoLo, affRaw, SL);
    hipLaunchKernelGGL(k2_mlp, dim3(392), dim3(256), 0, stream,
                       affRaw, lng, lnb, w1, b1, w2, b2, affRes);
    hipLaunchKernelGGL(k3a_pconv, dim3(32), dim3(256), 0, stream,
                       affRes, pw, part);
    hipLaunchKernelGGL(k3b_yt, dim3(8), dim3(256), 0, stream, part, pcb, out);
    // spatial path (k4a fused into k1)
    hipLaunchKernelGGL(k4b_softmax, dim3(16, 8), dim3(256), 0, stream, SL, WSUM);
    hipLaunchKernelGGL(k4c_vsum, dim3(16, 8, 2), dim3(256), 0, stream, v, WSUM, PS);
    hipLaunchKernelGGL(k4d_ys, dim3(32), dim3(256), 0, stream, PS, out);
}